// Round 1
// baseline (456.362 us; speedup 1.0000x reference)
//
#include <hip/hip_runtime.h>
#include <hip/hip_bf16.h>

#define B_  16
#define S_  2048
#define F_  800
#define E_  200
#define EP  224          // padded E, multiple of 32
#define M_  (B_ * S_)    // 32768

typedef __attribute__((ext_vector_type(8))) short short8;
typedef __attribute__((ext_vector_type(4))) float f32x4;

__device__ __forceinline__ unsigned short f2bf(float f) {
    __hip_bfloat16 h = __float2bfloat16(f);
    return *reinterpret_cast<unsigned short*>(&h);
}

__device__ __forceinline__ float gelu_exact(float x) {
    return 0.5f * x * (1.0f + erff(x * 0.70710678118654752440f));
}

// ---------------- Stage 1: Q/K/V = gelu(X @ W) ----------------
// grid (256, 3) blocks of 256 threads. Each block: 128 rows x 224 cols.
// sel 0 -> qbuf [M][EP], sel 1 -> kbuf [M][EP], sel 2 -> vtbuf [B][EP][S]
__global__ __launch_bounds__(256, 2)
void qkv_kernel(const float* __restrict__ x,
                const float* __restrict__ Wq,
                const float* __restrict__ Wk,
                const float* __restrict__ Wv,
                unsigned short* __restrict__ qbuf,
                unsigned short* __restrict__ kbuf,
                unsigned short* __restrict__ vtbuf) {
    const int sel = blockIdx.y;
    const float* W = (sel == 0) ? Wq : ((sel == 1) ? Wk : Wv);
    const int m0 = blockIdx.x * 128;
    const int t = threadIdx.x;
    const int lane = t & 63;
    const int w = t >> 6;

    __shared__ unsigned short Xs[128][40];   // 32 cols + pad to 40 (bank-friendly)
    __shared__ unsigned short Ws[EP][40];    // W^T tile: [col][k]

    f32x4 acc[2][14];
#pragma unroll
    for (int i = 0; i < 2; ++i)
#pragma unroll
        for (int j = 0; j < 14; ++j) acc[i][j] = (f32x4)0.0f;

    for (int kk = 0; kk < 25; ++kk) {
        const int k0 = kk * 32;
        // X tile: 128 x 32 fp32 -> bf16
        {
            int r = t >> 3;
            const int c = (t & 7) * 4;
#pragma unroll
            for (int it = 0; it < 4; ++it, r += 32) {
                const float4 v = *reinterpret_cast<const float4*>(
                    x + (size_t)(m0 + r) * F_ + k0 + c);
                ushort4 pk;
                pk.x = f2bf(v.x); pk.y = f2bf(v.y);
                pk.z = f2bf(v.z); pk.w = f2bf(v.w);
                *reinterpret_cast<ushort4*>(&Xs[r][c]) = pk;
            }
        }
        // W^T tile: Ws[c][k] = W[k0+k][c]  (c<200 real, else 0)
        if (t < EP) {
            const int c = t;
#pragma unroll 8
            for (int k = 0; k < 32; ++k) {
                float v = (c < E_) ? W[(size_t)(k0 + k) * E_ + c] : 0.0f;
                Ws[c][k] = f2bf(v);
            }
        }
        __syncthreads();

        const int rbase = w * 32 + (lane & 15);
        const int kq = (lane >> 4) * 8;
        short8 a0 = *reinterpret_cast<const short8*>(&Xs[rbase][kq]);
        short8 a1 = *reinterpret_cast<const short8*>(&Xs[rbase + 16][kq]);
#pragma unroll
        for (int n = 0; n < 14; ++n) {
            short8 b = *reinterpret_cast<const short8*>(&Ws[n * 16 + (lane & 15)][kq]);
            acc[0][n] = __builtin_amdgcn_mfma_f32_16x16x32_bf16(a0, b, acc[0][n], 0, 0, 0);
            acc[1][n] = __builtin_amdgcn_mfma_f32_16x16x32_bf16(a1, b, acc[1][n], 0, 0, 0);
        }
        __syncthreads();
    }

    // epilogue: gelu + store
    const int col0 = lane & 15;
    const int r4 = (lane >> 4) * 4;
#pragma unroll
    for (int mi = 0; mi < 2; ++mi) {
#pragma unroll
        for (int n = 0; n < 14; ++n) {
            const int col = n * 16 + col0;
            const int row = m0 + w * 32 + mi * 16 + r4;   // first of 4 consecutive rows
            if (sel < 2) {
                unsigned short* dst = (sel == 0) ? qbuf : kbuf;
#pragma unroll
                for (int tt = 0; tt < 4; ++tt)
                    dst[(size_t)(row + tt) * EP + col] = f2bf(gelu_exact(acc[mi][n][tt]));
            } else {
                const int bb = row >> 11, s = row & 2047;
                ushort4 pk;
                pk.x = f2bf(gelu_exact(acc[mi][n][0]));
                pk.y = f2bf(gelu_exact(acc[mi][n][1]));
                pk.z = f2bf(gelu_exact(acc[mi][n][2]));
                pk.w = f2bf(gelu_exact(acc[mi][n][3]));
                *reinterpret_cast<ushort4*>(
                    &vtbuf[((size_t)(bb * EP + col)) * S_ + s]) = pk;
            }
        }
    }
}

// ---------------- Stage 2: flash attention ----------------
// grid (16, 16) blocks of 512 threads (8 waves x 16 q-rows), BKV = 64
#define BQ  128
#define BKV 64

__global__ __launch_bounds__(512, 2)
void attn_kernel(const unsigned short* __restrict__ qbuf,
                 const unsigned short* __restrict__ kbuf,
                 const unsigned short* __restrict__ vtbuf,
                 float* __restrict__ out) {
    const int b = blockIdx.y;
    const int q0 = blockIdx.x * BQ;
    const int t = threadIdx.x;
    const int lane = t & 63;
    const int w = t >> 6;   // 0..7

    __shared__ unsigned short Ks[BKV][232];      // K tile, pitch 232 (bank-friendly)
    __shared__ unsigned short Vts[EP][72];       // V^T tile, pitch 72
    __shared__ unsigned short Plds[8][16][72];   // per-wave P staging

    const float scale = 0.03227486121839514f;    // 1/sqrt(960)

    // Q fragments (A-operand): row = q0 + w*16 + (lane&15), k-chunks of 8
    short8 qf[7];
    {
        const int qrow = q0 + w * 16 + (lane & 15);
        const unsigned short* qp = qbuf + (size_t)(b * S_ + qrow) * EP + (lane >> 4) * 8;
#pragma unroll
        for (int s = 0; s < 7; ++s)
            qf[s] = *reinterpret_cast<const short8*>(qp + s * 32);
    }

    f32x4 o[14];
#pragma unroll
    for (int i = 0; i < 14; ++i) o[i] = (f32x4)0.0f;
    float m_run[4], l_run[4];
#pragma unroll
    for (int i = 0; i < 4; ++i) { m_run[i] = -INFINITY; l_run[i] = 0.0f; }

    const int kq = (lane >> 4) * 8;

    for (int kt = 0; kt < S_ / BKV; ++kt) {
        const int kv0 = kt * BKV;
        // stage K tile: 64 rows x 224 cols = 28 x 16B segments per row
        for (int idx = t; idx < 64 * 28; idx += 512) {
            const int r = idx / 28, sg = idx % 28;
            const uint4 v = *reinterpret_cast<const uint4*>(
                kbuf + (size_t)(b * S_ + kv0 + r) * EP + sg * 8);
            *reinterpret_cast<uint4*>(&Ks[r][sg * 8]) = v;
        }
        // stage V^T tile: 224 rows x 64 = 8 x 16B segments per row
        for (int idx = t; idx < EP * 8; idx += 512) {
            const int e = idx >> 3, sg = idx & 7;
            const uint4 v = *reinterpret_cast<const uint4*>(
                vtbuf + (size_t)(b * EP + e) * S_ + kv0 + sg * 8);
            *reinterpret_cast<uint4*>(&Vts[e][sg * 8]) = v;
        }
        __syncthreads();

        // S = Q K^T  (per wave: 16 q-rows x 64 kv)
        f32x4 sacc[4];
#pragma unroll
        for (int n = 0; n < 4; ++n) {
            f32x4 a = (f32x4)0.0f;
            const unsigned short* krow = &Ks[n * 16 + (lane & 15)][0];
#pragma unroll
            for (int s = 0; s < 7; ++s) {
                short8 bf = *reinterpret_cast<const short8*>(krow + s * 32 + kq);
                a = __builtin_amdgcn_mfma_f32_16x16x32_bf16(qf[s], bf, a, 0, 0, 0);
            }
            sacc[n] = a;
        }

        // online softmax (C-layout: this lane owns rows (lane>>4)*4 + tt)
        float alpha[4], psum[4];
#pragma unroll
        for (int tt = 0; tt < 4; ++tt) {
            float mx = fmaxf(fmaxf(sacc[0][tt], sacc[1][tt]),
                             fmaxf(sacc[2][tt], sacc[3][tt]));
#pragma unroll
            for (int off = 1; off < 16; off <<= 1)
                mx = fmaxf(mx, __shfl_xor(mx, off, 64));
            const float mt = mx * scale;
            const float mn = fmaxf(m_run[tt], mt);
            alpha[tt] = expf(m_run[tt] - mn);
            m_run[tt] = mn;
            psum[tt] = 0.0f;
        }
#pragma unroll
        for (int n = 0; n < 4; ++n) {
#pragma unroll
            for (int tt = 0; tt < 4; ++tt) {
                const float p = expf(sacc[n][tt] * scale - m_run[tt]);
                psum[tt] += p;
                Plds[w][(lane >> 4) * 4 + tt][n * 16 + (lane & 15)] = f2bf(p);
            }
        }
#pragma unroll
        for (int tt = 0; tt < 4; ++tt) {
            float s = psum[tt];
#pragma unroll
            for (int off = 1; off < 16; off <<= 1) s += __shfl_xor(s, off, 64);
            l_run[tt] = l_run[tt] * alpha[tt] + s;
        }
#pragma unroll
        for (int i = 0; i < 14; ++i)
#pragma unroll
            for (int tt = 0; tt < 4; ++tt) o[i][tt] *= alpha[tt];

        __syncthreads();   // P visible; also all waves done before PV reads

        // O += P V   (A = P [16 x 64], B = V^T tile)
        short8 pf0 = *reinterpret_cast<const short8*>(&Plds[w][lane & 15][kq]);
        short8 pf1 = *reinterpret_cast<const short8*>(&Plds[w][lane & 15][32 + kq]);
#pragma unroll
        for (int n = 0; n < 14; ++n) {
            const unsigned short* vrow = &Vts[n * 16 + (lane & 15)][0];
            short8 b0 = *reinterpret_cast<const short8*>(vrow + kq);
            short8 b1 = *reinterpret_cast<const short8*>(vrow + 32 + kq);
            o[n] = __builtin_amdgcn_mfma_f32_16x16x32_bf16(pf0, b0, o[n], 0, 0, 0);
            o[n] = __builtin_amdgcn_mfma_f32_16x16x32_bf16(pf1, b1, o[n], 0, 0, 0);
        }
        __syncthreads();   // done with Ks/Vts before next stage overwrites
    }

    // normalize + write out (fp32, only e < 200)
#pragma unroll
    for (int n = 0; n < 13; ++n) {
        const int e = n * 16 + (lane & 15);
        if (e < E_) {
#pragma unroll
            for (int tt = 0; tt < 4; ++tt) {
                const int row = q0 + w * 16 + (lane >> 4) * 4 + tt;
                out[(size_t)(b * S_ + row) * E_ + e] = o[n][tt] / l_run[tt];
            }
        }
    }
}

extern "C" void kernel_launch(void* const* d_in, const int* in_sizes, int n_in,
                              void* d_out, int out_size, void* d_ws, size_t ws_size,
                              hipStream_t stream) {
    const float* x  = (const float*)d_in[0];
    const float* Wq = (const float*)d_in[1];
    const float* Wk = (const float*)d_in[2];
    const float* Wv = (const float*)d_in[3];
    float* out = (float*)d_out;

    unsigned short* qbuf  = (unsigned short*)d_ws;                 // [M_][EP]
    unsigned short* kbuf  = qbuf + (size_t)M_ * EP;                // [M_][EP]
    unsigned short* vtbuf = kbuf + (size_t)M_ * EP;                // [B_][EP][S_]
    // total ws use: 3 * 32768 * 224 * 2 = 44,040,192 bytes

    qkv_kernel<<<dim3(256, 3), 256, 0, stream>>>(x, Wq, Wk, Wv, qbuf, kbuf, vtbuf);
    attn_kernel<<<dim3(16, 16), 512, 0, stream>>>(qbuf, kbuf, vtbuf, out);
}

// Round 2
// 373.070 us; speedup vs baseline: 1.2233x; 1.2233x over previous
//
#include <hip/hip_runtime.h>
#include <hip/hip_bf16.h>

#define B_  16
#define S_  2048
#define F_  800
#define E_  200
#define EP  224          // padded E (multiple of 32)
#define KP  832          // padded K (13 * 64)
#define M_  (B_ * S_)    // 32768

typedef __attribute__((ext_vector_type(8))) short short8;
typedef __attribute__((ext_vector_type(4))) float f32x4;

__device__ __forceinline__ unsigned short f2bf(float f) {
    __hip_bfloat16 h = __float2bfloat16(f);
    return *reinterpret_cast<unsigned short*>(&h);
}

__device__ __forceinline__ float gelu_exact(float x) {
    return 0.5f * x * (1.0f + erff(x * 0.70710678118654752440f));
}

__device__ __forceinline__ void gload_lds16(const void* g, void* l) {
    __builtin_amdgcn_global_load_lds(
        (const __attribute__((address_space(1))) unsigned int*)g,
        (__attribute__((address_space(3))) unsigned int*)l, 16, 0, 0);
}

// ---------------- prep: X fp32 -> bf16 padded [M][KP] ----------------
// one thread per 8-element output chunk; grid exact: M*KP/8 / 256 blocks
__global__ __launch_bounds__(256)
void prep_x(const float* __restrict__ x, unsigned short* __restrict__ xb) {
    const int id = blockIdx.x * 256 + threadIdx.x;     // 0 .. M*104-1
    const int r  = id / (KP / 8);
    const int c8 = id % (KP / 8);
    ushort4 lo = {0, 0, 0, 0}, hi = {0, 0, 0, 0};
    if (c8 < F_ / 8) {
        const float4 a = *reinterpret_cast<const float4*>(x + (size_t)r * F_ + c8 * 8);
        const float4 b = *reinterpret_cast<const float4*>(x + (size_t)r * F_ + c8 * 8 + 4);
        lo.x = f2bf(a.x); lo.y = f2bf(a.y); lo.z = f2bf(a.z); lo.w = f2bf(a.w);
        hi.x = f2bf(b.x); hi.y = f2bf(b.y); hi.z = f2bf(b.z); hi.w = f2bf(b.w);
    }
    unsigned short* dst = xb + (size_t)r * KP + c8 * 8;
    *reinterpret_cast<ushort4*>(dst) = lo;
    *reinterpret_cast<ushort4*>(dst + 4) = hi;
}

// ---------------- prep: W^T bf16 padded wt[3][EP][KP] ----------------
__global__ __launch_bounds__(256)
void prep_w(const float* __restrict__ Wq, const float* __restrict__ Wk,
            const float* __restrict__ Wv, unsigned short* __restrict__ wt) {
    const int id = blockIdx.x * 256 + threadIdx.x;     // 0 .. 3*EP*KP-1
    const int sel = id / (EP * KP);
    const int rem = id % (EP * KP);
    const int e = rem / KP;
    const int k = rem % KP;
    const float* W = (sel == 0) ? Wq : ((sel == 1) ? Wk : Wv);
    float v = (e < E_ && k < F_) ? W[(size_t)k * E_ + e] : 0.0f;
    wt[id] = f2bf(v);
}

// ---------------- Stage 1 GEMM: Q/K/V = gelu(Xb @ W) ----------------
// grid (256, 3), 256 threads (4 waves, 2M x 2N). BM=128, BN=224, BK=64.
__global__ __launch_bounds__(256)
void gemm_qkv(const unsigned short* __restrict__ xb,
              const unsigned short* __restrict__ wt,
              unsigned short* __restrict__ qbuf,
              unsigned short* __restrict__ kbuf,
              unsigned short* __restrict__ vtbuf) {
    const int sel = blockIdx.y;
    const int m0 = blockIdx.x * 128;
    const int t = threadIdx.x;
    const int lane = t & 63;
    const int w = t >> 6;          // 0..3
    const int wr = w >> 1;         // M half
    const int wc = w & 1;          // N half
    const int ln15 = lane & 15;
    const int kq = (lane >> 4) * 8;

    __shared__ __align__(16) unsigned short Xs[128][64];   // linear (gload_lds)
    __shared__ __align__(16) unsigned short Ws[224][64];   // linear

    const unsigned short* wsel = wt + (size_t)sel * EP * KP;

    f32x4 acc[4][7];
#pragma unroll
    for (int i = 0; i < 4; ++i)
#pragma unroll
        for (int j = 0; j < 7; ++j) acc[i][j] = (f32x4)0.0f;

    const int rA = lane >> 3;          // 0..7 (row within 8-row chunk)
    const int cA = (lane & 7) * 8;     // element col within 64

    for (int kk = 0; kk < 13; ++kk) {
        const int k0 = kk * 64;
        // stage A tile: 16 x 1KB chunks, 4 per wave
#pragma unroll
        for (int i = 0; i < 4; ++i) {
            const int c = w * 4 + i;
            gload_lds16(xb + (size_t)(m0 + c * 8 + rA) * KP + k0 + cA, &Xs[c * 8][0]);
        }
        // stage B tile: 28 x 1KB chunks, 7 per wave
#pragma unroll
        for (int i = 0; i < 7; ++i) {
            const int c = w * 7 + i;
            gload_lds16(wsel + (size_t)(c * 8 + rA) * KP + k0 + cA, &Ws[c * 8][0]);
        }
        __syncthreads();

#pragma unroll
        for (int ks = 0; ks < 2; ++ks) {
            const int kb = ks * 32 + kq;
            short8 a[4];
#pragma unroll
            for (int rf = 0; rf < 4; ++rf)
                a[rf] = *reinterpret_cast<const short8*>(&Xs[wr * 64 + rf * 16 + ln15][kb]);
#pragma unroll
            for (int cf = 0; cf < 7; ++cf) {
                short8 bfr = *reinterpret_cast<const short8*>(
                    &Ws[wc * 112 + cf * 16 + ln15][kb]);
#pragma unroll
                for (int rf = 0; rf < 4; ++rf)
                    acc[rf][cf] = __builtin_amdgcn_mfma_f32_16x16x32_bf16(
                        a[rf], bfr, acc[rf][cf], 0, 0, 0);
            }
        }
        __syncthreads();
    }

    // epilogue: gelu + store
#pragma unroll
    for (int rf = 0; rf < 4; ++rf) {
        const int row = m0 + wr * 64 + rf * 16 + (lane >> 4) * 4;  // first of 4 rows
#pragma unroll
        for (int cf = 0; cf < 7; ++cf) {
            const int col = wc * 112 + cf * 16 + ln15;
            if (sel < 2) {
                unsigned short* dst = (sel == 0) ? qbuf : kbuf;
#pragma unroll
                for (int tt = 0; tt < 4; ++tt)
                    dst[(size_t)(row + tt) * EP + col] = f2bf(gelu_exact(acc[rf][cf][tt]));
            } else {
                const int bb = row >> 11, s = row & 2047;
                ushort4 pk;
                pk.x = f2bf(gelu_exact(acc[rf][cf][0]));
                pk.y = f2bf(gelu_exact(acc[rf][cf][1]));
                pk.z = f2bf(gelu_exact(acc[rf][cf][2]));
                pk.w = f2bf(gelu_exact(acc[rf][cf][3]));
                *reinterpret_cast<ushort4*>(
                    &vtbuf[((size_t)(bb * EP + col)) * S_ + s]) = pk;
            }
        }
    }
}

// ---------------- Stage 2: flash attention ----------------
#define BQ  128
#define BKV 64

__global__ __launch_bounds__(512, 2)
void attn_kernel(const unsigned short* __restrict__ qbuf,
                 const unsigned short* __restrict__ kbuf,
                 const unsigned short* __restrict__ vtbuf,
                 float* __restrict__ out) {
    const int b = blockIdx.y;
    const int q0 = blockIdx.x * BQ;
    const int t = threadIdx.x;
    const int lane = t & 63;
    const int w = t >> 6;   // 0..7

    __shared__ unsigned short Ks[BKV][232];
    __shared__ unsigned short Vts[EP][72];
    __shared__ unsigned short Plds[8][16][72];

    const float scale = 0.03227486121839514f;    // 1/sqrt(960)

    short8 qf[7];
    {
        const int qrow = q0 + w * 16 + (lane & 15);
        const unsigned short* qp = qbuf + (size_t)(b * S_ + qrow) * EP + (lane >> 4) * 8;
#pragma unroll
        for (int s = 0; s < 7; ++s)
            qf[s] = *reinterpret_cast<const short8*>(qp + s * 32);
    }

    f32x4 o[14];
#pragma unroll
    for (int i = 0; i < 14; ++i) o[i] = (f32x4)0.0f;
    float m_run[4], l_run[4];
#pragma unroll
    for (int i = 0; i < 4; ++i) { m_run[i] = -INFINITY; l_run[i] = 0.0f; }

    const int kq = (lane >> 4) * 8;

    for (int kt = 0; kt < S_ / BKV; ++kt) {
        const int kv0 = kt * BKV;
        for (int idx = t; idx < 64 * 28; idx += 512) {
            const int r = idx / 28, sg = idx % 28;
            const uint4 v = *reinterpret_cast<const uint4*>(
                kbuf + (size_t)(b * S_ + kv0 + r) * EP + sg * 8);
            *reinterpret_cast<uint4*>(&Ks[r][sg * 8]) = v;
        }
        for (int idx = t; idx < EP * 8; idx += 512) {
            const int e = idx >> 3, sg = idx & 7;
            const uint4 v = *reinterpret_cast<const uint4*>(
                vtbuf + (size_t)(b * EP + e) * S_ + kv0 + sg * 8);
            *reinterpret_cast<uint4*>(&Vts[e][sg * 8]) = v;
        }
        __syncthreads();

        f32x4 sacc[4];
#pragma unroll
        for (int n = 0; n < 4; ++n) {
            f32x4 a = (f32x4)0.0f;
            const unsigned short* krow = &Ks[n * 16 + (lane & 15)][0];
#pragma unroll
            for (int s = 0; s < 7; ++s) {
                short8 bf = *reinterpret_cast<const short8*>(krow + s * 32 + kq);
                a = __builtin_amdgcn_mfma_f32_16x16x32_bf16(qf[s], bf, a, 0, 0, 0);
            }
            sacc[n] = a;
        }

        float alpha[4], psum[4];
#pragma unroll
        for (int tt = 0; tt < 4; ++tt) {
            float mx = fmaxf(fmaxf(sacc[0][tt], sacc[1][tt]),
                             fmaxf(sacc[2][tt], sacc[3][tt]));
#pragma unroll
            for (int off = 1; off < 16; off <<= 1)
                mx = fmaxf(mx, __shfl_xor(mx, off, 64));
            const float mt = mx * scale;
            const float mn = fmaxf(m_run[tt], mt);
            alpha[tt] = expf(m_run[tt] - mn);
            m_run[tt] = mn;
            psum[tt] = 0.0f;
        }
#pragma unroll
        for (int n = 0; n < 4; ++n) {
#pragma unroll
            for (int tt = 0; tt < 4; ++tt) {
                const float p = expf(sacc[n][tt] * scale - m_run[tt]);
                psum[tt] += p;
                Plds[w][(lane >> 4) * 4 + tt][n * 16 + (lane & 15)] = f2bf(p);
            }
        }
#pragma unroll
        for (int tt = 0; tt < 4; ++tt) {
            float s = psum[tt];
#pragma unroll
            for (int off = 1; off < 16; off <<= 1) s += __shfl_xor(s, off, 64);
            l_run[tt] = l_run[tt] * alpha[tt] + s;
        }
#pragma unroll
        for (int i = 0; i < 14; ++i)
#pragma unroll
            for (int tt = 0; tt < 4; ++tt) o[i][tt] *= alpha[tt];

        __syncthreads();

        short8 pf0 = *reinterpret_cast<const short8*>(&Plds[w][lane & 15][kq]);
        short8 pf1 = *reinterpret_cast<const short8*>(&Plds[w][lane & 15][32 + kq]);
#pragma unroll
        for (int n = 0; n < 14; ++n) {
            const unsigned short* vrow = &Vts[n * 16 + (lane & 15)][0];
            short8 b0 = *reinterpret_cast<const short8*>(vrow + kq);
            short8 b1 = *reinterpret_cast<const short8*>(vrow + 32 + kq);
            o[n] = __builtin_amdgcn_mfma_f32_16x16x32_bf16(pf0, b0, o[n], 0, 0, 0);
            o[n] = __builtin_amdgcn_mfma_f32_16x16x32_bf16(pf1, b1, o[n], 0, 0, 0);
        }
        __syncthreads();
    }

#pragma unroll
    for (int n = 0; n < 13; ++n) {
        const int e = n * 16 + (lane & 15);
        if (e < E_) {
#pragma unroll
            for (int tt = 0; tt < 4; ++tt) {
                const int row = q0 + w * 16 + (lane >> 4) * 4 + tt;
                out[(size_t)(b * S_ + row) * E_ + e] = o[n][tt] / l_run[tt];
            }
        }
    }
}

extern "C" void kernel_launch(void* const* d_in, const int* in_sizes, int n_in,
                              void* d_out, int out_size, void* d_ws, size_t ws_size,
                              hipStream_t stream) {
    const float* x  = (const float*)d_in[0];
    const float* Wq = (const float*)d_in[1];
    const float* Wk = (const float*)d_in[2];
    const float* Wv = (const float*)d_in[3];
    float* out = (float*)d_out;

    unsigned short* xb    = (unsigned short*)d_ws;                 // [M_][KP]     54.5 MB
    unsigned short* wt    = xb + (size_t)M_ * KP;                  // [3][EP][KP]   1.1 MB
    unsigned short* qbuf  = wt + (size_t)3 * EP * KP;              // [M_][EP]     14.7 MB
    unsigned short* kbuf  = qbuf + (size_t)M_ * EP;                // [M_][EP]     14.7 MB
    unsigned short* vtbuf = kbuf + (size_t)M_ * EP;                // [B_][EP][S_] 14.7 MB
    // total ws use ~99.7 MB

    prep_x<<<dim3(M_ * (KP / 8) / 256), 256, 0, stream>>>(x, xb);
    prep_w<<<dim3(3 * EP * KP / 256), 256, 0, stream>>>(Wq, Wk, Wv, wt);
    gemm_qkv<<<dim3(256, 3), 256, 0, stream>>>(xb, wt, qbuf, kbuf, vtbuf);
    attn_kernel<<<dim3(16, 16), 512, 0, stream>>>(qbuf, kbuf, vtbuf, out);
}

// Round 3
// 294.779 us; speedup vs baseline: 1.5482x; 1.2656x over previous
//
#include <hip/hip_runtime.h>
#include <hip/hip_bf16.h>

#define B_  16
#define S_  2048
#define F_  800
#define E_  200
#define EP  224          // padded E (multiple of 32)
#define KP  832          // padded K (13 * 64)
#define KSP 256          // kbuf row pitch in shorts (32 x 16B slots, pow2 for swizzle)
#define M_  (B_ * S_)    // 32768

typedef __attribute__((ext_vector_type(8))) short short8;
typedef __attribute__((ext_vector_type(4))) float f32x4;

// scale = 1/sqrt(960); folded with log2(e) into Q so softmax runs in exp2 domain
#define QSCL (0.03227486121839514f * 1.4426950408889634f)

__device__ __forceinline__ unsigned short f2bf(float f) {
    __hip_bfloat16 h = __float2bfloat16(f);
    return *reinterpret_cast<unsigned short*>(&h);
}

__device__ __forceinline__ float gelu_exact(float x) {
    return 0.5f * x * (1.0f + erff(x * 0.70710678118654752440f));
}

__device__ __forceinline__ float exp2_fast(float x) {
    float r;
    asm("v_exp_f32 %0, %1" : "=v"(r) : "v"(x));
    return r;
}

__device__ __forceinline__ void gload_lds16(const void* g, void* l) {
    __builtin_amdgcn_global_load_lds(
        (const __attribute__((address_space(1))) unsigned int*)g,
        (__attribute__((address_space(3))) unsigned int*)l, 16, 0, 0);
}

// ---------------- prep: X fp32 -> bf16 padded [M][KP] ----------------
__global__ __launch_bounds__(256)
void prep_x(const float* __restrict__ x, unsigned short* __restrict__ xb) {
    const int id = blockIdx.x * 256 + threadIdx.x;     // 0 .. M*104-1
    const int r  = id / (KP / 8);
    const int c8 = id % (KP / 8);
    ushort4 lo = {0, 0, 0, 0}, hi = {0, 0, 0, 0};
    if (c8 < F_ / 8) {
        const float4 a = *reinterpret_cast<const float4*>(x + (size_t)r * F_ + c8 * 8);
        const float4 b = *reinterpret_cast<const float4*>(x + (size_t)r * F_ + c8 * 8 + 4);
        lo.x = f2bf(a.x); lo.y = f2bf(a.y); lo.z = f2bf(a.z); lo.w = f2bf(a.w);
        hi.x = f2bf(b.x); hi.y = f2bf(b.y); hi.z = f2bf(b.z); hi.w = f2bf(b.w);
    }
    unsigned short* dst = xb + (size_t)r * KP + c8 * 8;
    *reinterpret_cast<ushort4*>(dst) = lo;
    *reinterpret_cast<ushort4*>(dst + 4) = hi;
}

// ---------------- prep: W^T bf16 padded wt[3][EP][KP] ----------------
__global__ __launch_bounds__(256)
void prep_w(const float* __restrict__ Wq, const float* __restrict__ Wk,
            const float* __restrict__ Wv, unsigned short* __restrict__ wt) {
    const int id = blockIdx.x * 256 + threadIdx.x;
    const int sel = id / (EP * KP);
    const int rem = id % (EP * KP);
    const int e = rem / KP;
    const int k = rem % KP;
    const float* W = (sel == 0) ? Wq : ((sel == 1) ? Wk : Wv);
    float v = (e < E_ && k < F_) ? W[(size_t)k * E_ + e] : 0.0f;
    wt[id] = f2bf(v);
}

// ---------------- Stage 1 GEMM: Q/K/V = gelu(Xb @ W) ----------------
__global__ __launch_bounds__(256)
void gemm_qkv(const unsigned short* __restrict__ xb,
              const unsigned short* __restrict__ wt,
              unsigned short* __restrict__ qbuf,
              unsigned short* __restrict__ kbuf,
              unsigned short* __restrict__ vtbuf) {
    const int sel = blockIdx.y;
    const int m0 = blockIdx.x * 128;
    const int t = threadIdx.x;
    const int lane = t & 63;
    const int w = t >> 6;
    const int wr = w >> 1;
    const int wc = w & 1;
    const int ln15 = lane & 15;
    const int kq = (lane >> 4) * 8;

    __shared__ __align__(16) unsigned short Xs[128][64];
    __shared__ __align__(16) unsigned short Ws[224][64];

    const unsigned short* wsel = wt + (size_t)sel * EP * KP;

    f32x4 acc[4][7];
#pragma unroll
    for (int i = 0; i < 4; ++i)
#pragma unroll
        for (int j = 0; j < 7; ++j) acc[i][j] = (f32x4)0.0f;

    const int rA = lane >> 3;
    const int cA = (lane & 7) * 8;

    for (int kk = 0; kk < 13; ++kk) {
        const int k0 = kk * 64;
#pragma unroll
        for (int i = 0; i < 4; ++i) {
            const int c = w * 4 + i;
            gload_lds16(xb + (size_t)(m0 + c * 8 + rA) * KP + k0 + cA, &Xs[c * 8][0]);
        }
#pragma unroll
        for (int i = 0; i < 7; ++i) {
            const int c = w * 7 + i;
            gload_lds16(wsel + (size_t)(c * 8 + rA) * KP + k0 + cA, &Ws[c * 8][0]);
        }
        __syncthreads();

#pragma unroll
        for (int ks = 0; ks < 2; ++ks) {
            const int kb = ks * 32 + kq;
            short8 a[4];
#pragma unroll
            for (int rf = 0; rf < 4; ++rf)
                a[rf] = *reinterpret_cast<const short8*>(&Xs[wr * 64 + rf * 16 + ln15][kb]);
#pragma unroll
            for (int cf = 0; cf < 7; ++cf) {
                short8 bfr = *reinterpret_cast<const short8*>(
                    &Ws[wc * 112 + cf * 16 + ln15][kb]);
#pragma unroll
                for (int rf = 0; rf < 4; ++rf)
                    acc[rf][cf] = __builtin_amdgcn_mfma_f32_16x16x32_bf16(
                        a[rf], bfr, acc[rf][cf], 0, 0, 0);
            }
        }
        __syncthreads();
    }

    // epilogue: gelu + store (Q pre-scaled by QSCL; K at pitch KSP; V transposed)
#pragma unroll
    for (int rf = 0; rf < 4; ++rf) {
        const int row = m0 + wr * 64 + rf * 16 + (lane >> 4) * 4;
#pragma unroll
        for (int cf = 0; cf < 7; ++cf) {
            const int col = wc * 112 + cf * 16 + ln15;
            if (sel == 0) {
#pragma unroll
                for (int tt = 0; tt < 4; ++tt)
                    qbuf[(size_t)(row + tt) * EP + col] =
                        f2bf(gelu_exact(acc[rf][cf][tt]) * QSCL);
            } else if (sel == 1) {
#pragma unroll
                for (int tt = 0; tt < 4; ++tt)
                    kbuf[(size_t)(row + tt) * KSP + col] = f2bf(gelu_exact(acc[rf][cf][tt]));
            } else {
                const int bb = row >> 11, s = row & 2047;
                ushort4 pk;
                pk.x = f2bf(gelu_exact(acc[rf][cf][0]));
                pk.y = f2bf(gelu_exact(acc[rf][cf][1]));
                pk.z = f2bf(gelu_exact(acc[rf][cf][2]));
                pk.w = f2bf(gelu_exact(acc[rf][cf][3]));
                *reinterpret_cast<ushort4*>(
                    &vtbuf[((size_t)(bb * EP + col)) * S_ + s]) = pk;
            }
        }
    }
}

// ---------------- Stage 2: flash attention ----------------
// BQ=64, 4 waves x 16 q-rows, BKV=64; grid (32,16) -> 2 blocks/CU.
// K/V staged via global_load_lds with XOR slot swizzle (linear dest,
// inverse-swizzled per-lane source, swizzled read).
#define BQ  64
#define BKV 64

__global__ __launch_bounds__(256, 2)
void attn_kernel(const unsigned short* __restrict__ qbuf,
                 const unsigned short* __restrict__ kbuf,
                 const unsigned short* __restrict__ vtbuf,
                 float* __restrict__ out) {
    const int b = blockIdx.y;
    const int q0 = blockIdx.x * BQ;
    const int t = threadIdx.x;
    const int lane = t & 63;
    const int w = t >> 6;       // 0..3
    const int ln15 = lane & 15;
    const int g = lane >> 4;    // 0..3
    const int kq = g * 8;

    __shared__ __align__(16) unsigned short Ks[BKV * KSP];   // swizzled, pitch 256
    __shared__ __align__(16) unsigned short Vts[EP * 64];    // swizzled, pitch 64
    __shared__ __align__(16) unsigned short Plds[4][16][72];

    // Q fragments (pre-scaled by scale*log2e in stage 1)
    short8 qf[7];
    {
        const unsigned short* qp = qbuf + (size_t)(b * S_ + q0 + w * 16 + ln15) * EP + kq;
#pragma unroll
        for (int s = 0; s < 7; ++s)
            qf[s] = *reinterpret_cast<const short8*>(qp + s * 32);
    }

    f32x4 o[14];
#pragma unroll
    for (int i = 0; i < 14; ++i) o[i] = (f32x4)0.0f;
    float m_run[4], l_run[4];
#pragma unroll
    for (int i = 0; i < 4; ++i) { m_run[i] = -INFINITY; l_run[i] = 0.0f; }

    const unsigned short* kb_b = kbuf + (size_t)b * S_ * KSP;
    const unsigned short* vt_b = vtbuf + (size_t)b * EP * S_;

    for (int kt = 0; kt < S_ / BKV; ++kt) {
        const int kv0 = kt * BKV;
        // stage K tile: 32 x 1KB calls (2 rows each), 8 per wave
        {
            const int r_in = lane >> 5;       // 0/1
            const int p = lane & 31;          // physical 16B slot
#pragma unroll
            for (int i = 0; i < 8; ++i) {
                const int j = w * 8 + i;
                const int row = 2 * j + r_in;
                gload_lds16(kb_b + (size_t)(kv0 + row) * KSP + ((p ^ (row & 7)) * 8),
                            &Ks[j * 512]);
            }
        }
        // stage V^T tile: 28 x 1KB calls (8 rows each), 7 per wave
        {
            const int r_in = lane >> 3;       // 0..7
            const int p = lane & 7;
#pragma unroll
            for (int i = 0; i < 7; ++i) {
                const int j = w * 7 + i;
                const int row = 8 * j + r_in;
                gload_lds16(vt_b + (size_t)row * S_ + kv0 + ((p ^ (row & 7)) * 8),
                            &Vts[j * 512]);
            }
        }
        __syncthreads();

        // S = Q K^T  (per wave: 16 q-rows x 64 kv); already in log2 units
        f32x4 sacc[4];
#pragma unroll
        for (int n = 0; n < 4; ++n) {
            f32x4 a = (f32x4)0.0f;
            const int krow = n * 16 + ln15;
            const unsigned short* kr = &Ks[krow * KSP];
            const int rx = krow & 7;
#pragma unroll
            for (int s = 0; s < 7; ++s) {
                short8 bf = *reinterpret_cast<const short8*>(kr + (((s * 4 + g) ^ rx) * 8));
                a = __builtin_amdgcn_mfma_f32_16x16x32_bf16(qf[s], bf, a, 0, 0, 0);
            }
            sacc[n] = a;
        }

        // online softmax in exp2 domain, defer-rescale (THR=8)
        float mx[4];
#pragma unroll
        for (int tt = 0; tt < 4; ++tt) {
            float m0 = fmaxf(fmaxf(sacc[0][tt], sacc[1][tt]),
                             fmaxf(sacc[2][tt], sacc[3][tt]));
#pragma unroll
            for (int off = 1; off < 16; off <<= 1)
                m0 = fmaxf(m0, __shfl_xor(m0, off, 64));
            mx[tt] = m0;
        }
        const bool need = (mx[0] > m_run[0] + 8.0f) || (mx[1] > m_run[1] + 8.0f) ||
                          (mx[2] > m_run[2] + 8.0f) || (mx[3] > m_run[3] + 8.0f);
        if (__any(need)) {
#pragma unroll
            for (int tt = 0; tt < 4; ++tt) {
                const float mn = fmaxf(m_run[tt], mx[tt]);
                const float al = exp2_fast(m_run[tt] - mn);
                m_run[tt] = mn;
                l_run[tt] *= al;
#pragma unroll
                for (int i = 0; i < 14; ++i) o[i][tt] *= al;
            }
        }
        float psum[4] = {0.0f, 0.0f, 0.0f, 0.0f};
#pragma unroll
        for (int n = 0; n < 4; ++n)
#pragma unroll
            for (int tt = 0; tt < 4; ++tt) {
                const float p = exp2_fast(sacc[n][tt] - m_run[tt]);
                psum[tt] += p;
                Plds[w][g * 4 + tt][n * 16 + ln15] = f2bf(p);
            }
#pragma unroll
        for (int tt = 0; tt < 4; ++tt) {
            float s = psum[tt];
#pragma unroll
            for (int off = 1; off < 16; off <<= 1) s += __shfl_xor(s, off, 64);
            l_run[tt] += s;
        }

        // O += P V  (Plds is per-wave: no barrier needed before reading it)
        short8 pf0 = *reinterpret_cast<const short8*>(&Plds[w][ln15][kq]);
        short8 pf1 = *reinterpret_cast<const short8*>(&Plds[w][ln15][32 + kq]);
#pragma unroll
        for (int n = 0; n < 14; ++n) {
            const int vrow = n * 16 + ln15;
            const unsigned short* vr = &Vts[vrow * 64];
            const int rx = vrow & 7;
            short8 b0 = *reinterpret_cast<const short8*>(vr + ((g ^ rx) * 8));
            short8 b1 = *reinterpret_cast<const short8*>(vr + (((4 + g) ^ rx) * 8));
            o[n] = __builtin_amdgcn_mfma_f32_16x16x32_bf16(pf0, b0, o[n], 0, 0, 0);
            o[n] = __builtin_amdgcn_mfma_f32_16x16x32_bf16(pf1, b1, o[n], 0, 0, 0);
        }
        __syncthreads();   // all waves done with Ks/Vts before next staging
    }

    // normalize + write out
#pragma unroll
    for (int tt = 0; tt < 4; ++tt) {
        const float inv = 1.0f / l_run[tt];
        const int row = q0 + w * 16 + g * 4 + tt;
        float* op = out + (size_t)(b * S_ + row) * E_;
#pragma unroll
        for (int n = 0; n < 13; ++n) {
            const int e = n * 16 + ln15;
            if (e < E_) op[e] = o[n][tt] * inv;
        }
    }
}

extern "C" void kernel_launch(void* const* d_in, const int* in_sizes, int n_in,
                              void* d_out, int out_size, void* d_ws, size_t ws_size,
                              hipStream_t stream) {
    const float* x  = (const float*)d_in[0];
    const float* Wq = (const float*)d_in[1];
    const float* Wk = (const float*)d_in[2];
    const float* Wv = (const float*)d_in[3];
    float* out = (float*)d_out;

    unsigned short* xb    = (unsigned short*)d_ws;                 // [M_][KP]
    unsigned short* wt    = xb + (size_t)M_ * KP;                  // [3][EP][KP]
    unsigned short* qbuf  = wt + (size_t)3 * EP * KP;              // [M_][EP]
    unsigned short* kbuf  = qbuf + (size_t)M_ * EP;                // [M_][KSP]
    unsigned short* vtbuf = kbuf + (size_t)M_ * KSP;               // [B_][EP][S_]
    // total ws use ~102 MB

    prep_x<<<dim3(M_ * (KP / 8) / 256), 256, 0, stream>>>(x, xb);
    prep_w<<<dim3(3 * EP * KP / 256), 256, 0, stream>>>(Wq, Wk, Wv, wt);
    gemm_qkv<<<dim3(256, 3), 256, 0, stream>>>(xb, wt, qbuf, kbuf, vtbuf);
    attn_kernel<<<dim3(S_ / BQ, B_), 256, 0, stream>>>(qbuf, kbuf, vtbuf, out);
}

// Round 4
// 213.741 us; speedup vs baseline: 2.1351x; 1.3791x over previous
//
#include <hip/hip_runtime.h>
#include <hip/hip_bf16.h>

#define B_  16
#define S_  2048
#define F_  800
#define E_  200
#define EP  224          // padded E (multiple of 32)
#define KP  832          // padded K (13 * 64)
#define KSP 256          // kbuf row pitch in shorts (32 x 16B slots, pow2 for swizzle)
#define M_  (B_ * S_)    // 32768

typedef __attribute__((ext_vector_type(8))) short short8;
typedef __attribute__((ext_vector_type(4))) float f32x4;

// scale = 1/sqrt(960); folded with log2(e) into Q so softmax runs in exp2 domain
#define QSCL (0.03227486121839514f * 1.4426950408889634f)

__device__ __forceinline__ unsigned short f2bf(float f) {
    __hip_bfloat16 h = __float2bfloat16(f);
    return *reinterpret_cast<unsigned short*>(&h);
}

__device__ __forceinline__ float exp2_fast(float x) {
    float r;
    asm("v_exp_f32 %0, %1" : "=v"(r) : "v"(x));
    return r;
}

__device__ __forceinline__ float rcp_fast(float x) {
    float r;
    asm("v_rcp_f32 %0, %1" : "=v"(r) : "v"(x));
    return r;
}

// tanh-form GELU (max |err| vs exact ~5e-4, below bf16 noise here):
// gelu(x) = x * sigmoid(2*0.79788456*(x + 0.044715 x^3))
__device__ __forceinline__ float gelu_fast(float x) {
    const float i = x + 0.044715f * x * x * x;
    const float z = 2.302265314f * i;              // 2*0.79788456*log2(e) * i
    return x * rcp_fast(1.0f + exp2_fast(-z));
}

__device__ __forceinline__ void gload_lds16(const void* g, void* l) {
    __builtin_amdgcn_global_load_lds(
        (const __attribute__((address_space(1))) unsigned int*)g,
        (__attribute__((address_space(3))) unsigned int*)l, 16, 0, 0);
}

// ---------------- prep: X fp32 -> bf16 padded [M][KP] ----------------
__global__ __launch_bounds__(256)
void prep_x(const float* __restrict__ x, unsigned short* __restrict__ xb) {
    const int id = blockIdx.x * 256 + threadIdx.x;     // 0 .. M*104-1
    const int r  = id / (KP / 8);
    const int c8 = id % (KP / 8);
    ushort4 lo = {0, 0, 0, 0}, hi = {0, 0, 0, 0};
    if (c8 < F_ / 8) {
        const float4 a = *reinterpret_cast<const float4*>(x + (size_t)r * F_ + c8 * 8);
        const float4 b = *reinterpret_cast<const float4*>(x + (size_t)r * F_ + c8 * 8 + 4);
        lo.x = f2bf(a.x); lo.y = f2bf(a.y); lo.z = f2bf(a.z); lo.w = f2bf(a.w);
        hi.x = f2bf(b.x); hi.y = f2bf(b.y); hi.z = f2bf(b.z); hi.w = f2bf(b.w);
    }
    unsigned short* dst = xb + (size_t)r * KP + c8 * 8;
    *reinterpret_cast<ushort4*>(dst) = lo;
    *reinterpret_cast<ushort4*>(dst + 4) = hi;
}

// ---------------- prep: W^T bf16 padded wt[3][EP][KP] ----------------
__global__ __launch_bounds__(256)
void prep_w(const float* __restrict__ Wq, const float* __restrict__ Wk,
            const float* __restrict__ Wv, unsigned short* __restrict__ wt) {
    const int id = blockIdx.x * 256 + threadIdx.x;
    const int sel = id / (EP * KP);
    const int rem = id % (EP * KP);
    const int e = rem / KP;
    const int k = rem % KP;
    const float* W = (sel == 0) ? Wq : ((sel == 1) ? Wk : Wv);
    float v = (e < E_ && k < F_) ? W[(size_t)k * E_ + e] : 0.0f;
    wt[id] = f2bf(v);
}

// ---------------- Stage 1 GEMM: Q/K/V = gelu(Xb @ W) ----------------
// grid (256, 3), 256 threads (4 waves, 2M x 2N). BM=128, BN=224, BK=64.
// 2-phase double-buffered pipeline; XOR slot-swizzled LDS tiles.
#define STAGE(XB, WB, KK) do {                                                   \
    const int k0s = (KK) * 64;                                                   \
    _Pragma("unroll")                                                            \
    for (int i = 0; i < 4; ++i) {                                                \
        const int c = w * 4 + i;                                                 \
        gload_lds16(xb + (size_t)(m0 + c * 8 + rA) * KP + k0s + cS,              \
                    &XB[c * 8][0]);                                              \
    }                                                                            \
    _Pragma("unroll")                                                            \
    for (int i = 0; i < 7; ++i) {                                                \
        const int c = w * 7 + i;                                                 \
        gload_lds16(wsel + (size_t)(c * 8 + rA) * KP + k0s + cS,                 \
                    &WB[c * 8][0]);                                              \
    }                                                                            \
} while (0)

#define COMPUTE(XB, WB) do {                                                     \
    _Pragma("unroll")                                                            \
    for (int ks = 0; ks < 2; ++ks) {                                             \
        short8 afr[4];                                                           \
        _Pragma("unroll")                                                        \
        for (int rf = 0; rf < 4; ++rf) {                                         \
            const int row = wr * 64 + rf * 16 + ln15;                            \
            afr[rf] = *reinterpret_cast<const short8*>(                          \
                &XB[row][((ks * 4 + g) ^ (row & 7)) * 8]);                       \
        }                                                                        \
        _Pragma("unroll")                                                        \
        for (int cf = 0; cf < 7; ++cf) {                                         \
            const int row = wc * 112 + cf * 16 + ln15;                           \
            short8 bfr = *reinterpret_cast<const short8*>(                       \
                &WB[row][((ks * 4 + g) ^ (row & 7)) * 8]);                       \
            _Pragma("unroll")                                                    \
            for (int rf = 0; rf < 4; ++rf)                                       \
                acc[rf][cf] = __builtin_amdgcn_mfma_f32_16x16x32_bf16(           \
                    afr[rf], bfr, acc[rf][cf], 0, 0, 0);                         \
        }                                                                        \
    }                                                                            \
} while (0)

__global__ __launch_bounds__(256)
void gemm_qkv(const unsigned short* __restrict__ xb,
              const unsigned short* __restrict__ wt,
              unsigned short* __restrict__ qbuf,
              unsigned short* __restrict__ kbuf,
              unsigned short* __restrict__ vtbuf) {
    const int sel = blockIdx.y;
    const int m0 = blockIdx.x * 128;
    const int t = threadIdx.x;
    const int lane = t & 63;
    const int w = t >> 6;
    const int wr = w >> 1;
    const int wc = w & 1;
    const int ln15 = lane & 15;
    const int g = lane >> 4;

    __shared__ __align__(16) unsigned short X0s[128][64];
    __shared__ __align__(16) unsigned short W0s[224][64];
    __shared__ __align__(16) unsigned short X1s[128][64];
    __shared__ __align__(16) unsigned short W1s[224][64];

    const unsigned short* wsel = wt + (size_t)sel * EP * KP;

    f32x4 acc[4][7];
#pragma unroll
    for (int i = 0; i < 4; ++i)
#pragma unroll
        for (int j = 0; j < 7; ++j) acc[i][j] = (f32x4)0.0f;

    const int rA = lane >> 3;                       // row within 8-row chunk
    const int cS = ((lane & 7) ^ rA) * 8;           // inverse-swizzled source slot

    STAGE(X0s, W0s, 0);
    __syncthreads();
#pragma unroll
    for (int p = 0; p < 6; ++p) {
        STAGE(X1s, W1s, 2 * p + 1);
        COMPUTE(X0s, W0s);
        __syncthreads();
        STAGE(X0s, W0s, 2 * p + 2);
        COMPUTE(X1s, W1s);
        __syncthreads();
    }
    COMPUTE(X0s, W0s);                              // kk = 12

    // epilogue: gelu + store (Q pre-scaled by QSCL; K at pitch KSP; V transposed)
#pragma unroll
    for (int rf = 0; rf < 4; ++rf) {
        const int row = m0 + wr * 64 + rf * 16 + g * 4;
#pragma unroll
        for (int cf = 0; cf < 7; ++cf) {
            const int col = wc * 112 + cf * 16 + ln15;
            if (sel == 0) {
#pragma unroll
                for (int tt = 0; tt < 4; ++tt)
                    qbuf[(size_t)(row + tt) * EP + col] =
                        f2bf(gelu_fast(acc[rf][cf][tt]) * QSCL);
            } else if (sel == 1) {
#pragma unroll
                for (int tt = 0; tt < 4; ++tt)
                    kbuf[(size_t)(row + tt) * KSP + col] = f2bf(gelu_fast(acc[rf][cf][tt]));
            } else {
                const int bb = row >> 11, s = row & 2047;
                ushort4 pk;
                pk.x = f2bf(gelu_fast(acc[rf][cf][0]));
                pk.y = f2bf(gelu_fast(acc[rf][cf][1]));
                pk.z = f2bf(gelu_fast(acc[rf][cf][2]));
                pk.w = f2bf(gelu_fast(acc[rf][cf][3]));
                *reinterpret_cast<ushort4*>(
                    &vtbuf[((size_t)(bb * EP + col)) * S_ + s]) = pk;
            }
        }
    }
}

// ---------------- Stage 2: flash attention ----------------
// BQ=64, 4 waves x 16 q-rows, BKV=64; grid (32,16) -> 2 blocks/CU.
#define BQ  64
#define BKV 64

__global__ __launch_bounds__(256, 2)
void attn_kernel(const unsigned short* __restrict__ qbuf,
                 const unsigned short* __restrict__ kbuf,
                 const unsigned short* __restrict__ vtbuf,
                 float* __restrict__ out) {
    const int b = blockIdx.y;
    const int q0 = blockIdx.x * BQ;
    const int t = threadIdx.x;
    const int lane = t & 63;
    const int w = t >> 6;       // 0..3
    const int ln15 = lane & 15;
    const int g = lane >> 4;    // 0..3
    const int kq = g * 8;

    __shared__ __align__(16) unsigned short Ks[BKV * KSP];   // swizzled, pitch 256
    __shared__ __align__(16) unsigned short Vts[EP * 64];    // swizzled, pitch 64
    __shared__ __align__(16) unsigned short Plds[4][16][72];

    short8 qf[7];
    {
        const unsigned short* qp = qbuf + (size_t)(b * S_ + q0 + w * 16 + ln15) * EP + kq;
#pragma unroll
        for (int s = 0; s < 7; ++s)
            qf[s] = *reinterpret_cast<const short8*>(qp + s * 32);
    }

    f32x4 o[14];
#pragma unroll
    for (int i = 0; i < 14; ++i) o[i] = (f32x4)0.0f;
    float m_run[4], l_run[4];
#pragma unroll
    for (int i = 0; i < 4; ++i) { m_run[i] = -INFINITY; l_run[i] = 0.0f; }

    const unsigned short* kb_b = kbuf + (size_t)b * S_ * KSP;
    const unsigned short* vt_b = vtbuf + (size_t)b * EP * S_;

    for (int kt = 0; kt < S_ / BKV; ++kt) {
        const int kv0 = kt * BKV;
        {
            const int r_in = lane >> 5;
            const int p = lane & 31;
#pragma unroll
            for (int i = 0; i < 8; ++i) {
                const int j = w * 8 + i;
                const int row = 2 * j + r_in;
                gload_lds16(kb_b + (size_t)(kv0 + row) * KSP + ((p ^ (row & 7)) * 8),
                            &Ks[j * 512]);
            }
        }
        {
            const int r_in = lane >> 3;
            const int p = lane & 7;
#pragma unroll
            for (int i = 0; i < 7; ++i) {
                const int j = w * 7 + i;
                const int row = 8 * j + r_in;
                gload_lds16(vt_b + (size_t)row * S_ + kv0 + ((p ^ (row & 7)) * 8),
                            &Vts[j * 512]);
            }
        }
        __syncthreads();

        f32x4 sacc[4];
#pragma unroll
        for (int n = 0; n < 4; ++n) {
            f32x4 a = (f32x4)0.0f;
            const int krow = n * 16 + ln15;
            const unsigned short* kr = &Ks[krow * KSP];
            const int rx = krow & 7;
#pragma unroll
            for (int s = 0; s < 7; ++s) {
                short8 bf = *reinterpret_cast<const short8*>(kr + (((s * 4 + g) ^ rx) * 8));
                a = __builtin_amdgcn_mfma_f32_16x16x32_bf16(qf[s], bf, a, 0, 0, 0);
            }
            sacc[n] = a;
        }

        float mx[4];
#pragma unroll
        for (int tt = 0; tt < 4; ++tt) {
            float m0 = fmaxf(fmaxf(sacc[0][tt], sacc[1][tt]),
                             fmaxf(sacc[2][tt], sacc[3][tt]));
#pragma unroll
            for (int off = 1; off < 16; off <<= 1)
                m0 = fmaxf(m0, __shfl_xor(m0, off, 64));
            mx[tt] = m0;
        }
        const bool need = (mx[0] > m_run[0] + 8.0f) || (mx[1] > m_run[1] + 8.0f) ||
                          (mx[2] > m_run[2] + 8.0f) || (mx[3] > m_run[3] + 8.0f);
        if (__any(need)) {
#pragma unroll
            for (int tt = 0; tt < 4; ++tt) {
                const float mn = fmaxf(m_run[tt], mx[tt]);
                const float al = exp2_fast(m_run[tt] - mn);
                m_run[tt] = mn;
                l_run[tt] *= al;
#pragma unroll
                for (int i = 0; i < 14; ++i) o[i][tt] *= al;
            }
        }
        float psum[4] = {0.0f, 0.0f, 0.0f, 0.0f};
#pragma unroll
        for (int n = 0; n < 4; ++n)
#pragma unroll
            for (int tt = 0; tt < 4; ++tt) {
                const float p = exp2_fast(sacc[n][tt] - m_run[tt]);
                psum[tt] += p;
                Plds[w][g * 4 + tt][n * 16 + ln15] = f2bf(p);
            }
#pragma unroll
        for (int tt = 0; tt < 4; ++tt) {
            float s = psum[tt];
#pragma unroll
            for (int off = 1; off < 16; off <<= 1) s += __shfl_xor(s, off, 64);
            l_run[tt] += s;
        }

        short8 pf0 = *reinterpret_cast<const short8*>(&Plds[w][ln15][kq]);
        short8 pf1 = *reinterpret_cast<const short8*>(&Plds[w][ln15][32 + kq]);
#pragma unroll
        for (int n = 0; n < 14; ++n) {
            const int vrow = n * 16 + ln15;
            const unsigned short* vr = &Vts[vrow * 64];
            const int rx = vrow & 7;
            short8 b0 = *reinterpret_cast<const short8*>(vr + ((g ^ rx) * 8));
            short8 b1 = *reinterpret_cast<const short8*>(vr + (((4 + g) ^ rx) * 8));
            o[n] = __builtin_amdgcn_mfma_f32_16x16x32_bf16(pf0, b0, o[n], 0, 0, 0);
            o[n] = __builtin_amdgcn_mfma_f32_16x16x32_bf16(pf1, b1, o[n], 0, 0, 0);
        }
        __syncthreads();
    }

#pragma unroll
    for (int tt = 0; tt < 4; ++tt) {
        const float inv = 1.0f / l_run[tt];
        const int row = q0 + w * 16 + g * 4 + tt;
        float* op = out + (size_t)(b * S_ + row) * E_;
#pragma unroll
        for (int n = 0; n < 13; ++n) {
            const int e = n * 16 + ln15;
            if (e < E_) op[e] = o[n][tt] * inv;
        }
    }
}

extern "C" void kernel_launch(void* const* d_in, const int* in_sizes, int n_in,
                              void* d_out, int out_size, void* d_ws, size_t ws_size,
                              hipStream_t stream) {
    const float* x  = (const float*)d_in[0];
    const float* Wq = (const float*)d_in[1];
    const float* Wk = (const float*)d_in[2];
    const float* Wv = (const float*)d_in[3];
    float* out = (float*)d_out;

    unsigned short* xb    = (unsigned short*)d_ws;                 // [M_][KP]
    unsigned short* wt    = xb + (size_t)M_ * KP;                  // [3][EP][KP]
    unsigned short* qbuf  = wt + (size_t)3 * EP * KP;              // [M_][EP]
    unsigned short* kbuf  = qbuf + (size_t)M_ * EP;                // [M_][KSP]
    unsigned short* vtbuf = kbuf + (size_t)M_ * KSP;               // [B_][EP][S_]

    prep_x<<<dim3(M_ * (KP / 8) / 256), 256, 0, stream>>>(x, xb);
    prep_w<<<dim3(3 * EP * KP / 256), 256, 0, stream>>>(Wq, Wk, Wv, wt);
    gemm_qkv<<<dim3(256, 3), 256, 0, stream>>>(xb, wt, qbuf, kbuf, vtbuf);
    attn_kernel<<<dim3(S_ / BQ, B_), 256, 0, stream>>>(qbuf, kbuf, vtbuf, out);
}

// Round 5
// 204.446 us; speedup vs baseline: 2.2322x; 1.0455x over previous
//
#include <hip/hip_runtime.h>
#include <hip/hip_bf16.h>

#define B_  16
#define S_  2048
#define F_  800
#define E_  200
#define EP  224          // padded E (multiple of 32)
#define KP  832          // padded K (13 * 64)
#define KSP 256          // kbuf row pitch in shorts (32 x 16B slots, pow2 for swizzle)
#define M_  (B_ * S_)    // 32768

typedef __attribute__((ext_vector_type(8))) short short8;
typedef __attribute__((ext_vector_type(4))) float f32x4;

// scale = 1/sqrt(960); folded with log2(e) into Q so softmax runs in exp2 domain
#define QSCL (0.03227486121839514f * 1.4426950408889634f)

__device__ __forceinline__ unsigned short f2bf(float f) {
    __hip_bfloat16 h = __float2bfloat16(f);
    return *reinterpret_cast<unsigned short*>(&h);
}

__device__ __forceinline__ float exp2_fast(float x) {
    float r;
    asm("v_exp_f32 %0, %1" : "=v"(r) : "v"(x));
    return r;
}

__device__ __forceinline__ float rcp_fast(float x) {
    float r;
    asm("v_rcp_f32 %0, %1" : "=v"(r) : "v"(x));
    return r;
}

// tanh-form GELU (max |err| vs exact ~5e-4, below bf16 noise here)
__device__ __forceinline__ float gelu_fast(float x) {
    const float i = x + 0.044715f * x * x * x;
    const float z = 2.302265314f * i;              // 2*0.79788456*log2(e) * i
    return x * rcp_fast(1.0f + exp2_fast(-z));
}

__device__ __forceinline__ void gload_lds16(const void* g, void* l) {
    __builtin_amdgcn_global_load_lds(
        (const __attribute__((address_space(1))) unsigned int*)g,
        (__attribute__((address_space(3))) unsigned int*)l, 16, 0, 0);
}

// ---------------- prep: X fp32 -> bf16 padded [M][KP] ----------------
__global__ __launch_bounds__(256)
void prep_x(const float* __restrict__ x, unsigned short* __restrict__ xb) {
    const int id = blockIdx.x * 256 + threadIdx.x;
    const int r  = id / (KP / 8);
    const int c8 = id % (KP / 8);
    ushort4 lo = {0, 0, 0, 0}, hi = {0, 0, 0, 0};
    if (c8 < F_ / 8) {
        const float4 a = *reinterpret_cast<const float4*>(x + (size_t)r * F_ + c8 * 8);
        const float4 b = *reinterpret_cast<const float4*>(x + (size_t)r * F_ + c8 * 8 + 4);
        lo.x = f2bf(a.x); lo.y = f2bf(a.y); lo.z = f2bf(a.z); lo.w = f2bf(a.w);
        hi.x = f2bf(b.x); hi.y = f2bf(b.y); hi.z = f2bf(b.z); hi.w = f2bf(b.w);
    }
    unsigned short* dst = xb + (size_t)r * KP + c8 * 8;
    *reinterpret_cast<ushort4*>(dst) = lo;
    *reinterpret_cast<ushort4*>(dst + 4) = hi;
}

// ---------------- prep: W^T bf16 padded wt[3][EP][KP] ----------------
__global__ __launch_bounds__(256)
void prep_w(const float* __restrict__ Wq, const float* __restrict__ Wk,
            const float* __restrict__ Wv, unsigned short* __restrict__ wt) {
    const int id = blockIdx.x * 256 + threadIdx.x;
    const int sel = id / (EP * KP);
    const int rem = id % (EP * KP);
    const int e = rem / KP;
    const int k = rem % KP;
    const float* W = (sel == 0) ? Wq : ((sel == 1) ? Wk : Wv);
    float v = (e < E_ && k < F_) ? W[(size_t)k * E_ + e] : 0.0f;
    wt[id] = f2bf(v);
}

// ---------------- Stage 1 GEMM: Q/K/V = gelu(Xb @ W) ----------------
#define STAGE(XB, WB, KK) do {                                                   \
    const int k0s = (KK) * 64;                                                   \
    _Pragma("unroll")                                                            \
    for (int i = 0; i < 4; ++i) {                                                \
        const int c = w * 4 + i;                                                 \
        gload_lds16(xb + (size_t)(m0 + c * 8 + rA) * KP + k0s + cS,              \
                    &XB[c * 8][0]);                                              \
    }                                                                            \
    _Pragma("unroll")                                                            \
    for (int i = 0; i < 7; ++i) {                                                \
        const int c = w * 7 + i;                                                 \
        gload_lds16(wsel + (size_t)(c * 8 + rA) * KP + k0s + cS,                 \
                    &WB[c * 8][0]);                                              \
    }                                                                            \
} while (0)

#define COMPUTE(XB, WB) do {                                                     \
    _Pragma("unroll")                                                            \
    for (int ks = 0; ks < 2; ++ks) {                                             \
        short8 afr[4];                                                           \
        _Pragma("unroll")                                                        \
        for (int rf = 0; rf < 4; ++rf) {                                         \
            const int row = wr * 64 + rf * 16 + ln15;                            \
            afr[rf] = *reinterpret_cast<const short8*>(                          \
                &XB[row][((ks * 4 + g) ^ (row & 7)) * 8]);                       \
        }                                                                        \
        _Pragma("unroll")                                                        \
        for (int cf = 0; cf < 7; ++cf) {                                         \
            const int row = wc * 112 + cf * 16 + ln15;                           \
            short8 bfr = *reinterpret_cast<const short8*>(                       \
                &WB[row][((ks * 4 + g) ^ (row & 7)) * 8]);                       \
            _Pragma("unroll")                                                    \
            for (int rf = 0; rf < 4; ++rf)                                       \
                acc[rf][cf] = __builtin_amdgcn_mfma_f32_16x16x32_bf16(           \
                    afr[rf], bfr, acc[rf][cf], 0, 0, 0);                         \
        }                                                                        \
    }                                                                            \
} while (0)

__global__ __launch_bounds__(256)
void gemm_qkv(const unsigned short* __restrict__ xb,
              const unsigned short* __restrict__ wt,
              unsigned short* __restrict__ qbuf,
              unsigned short* __restrict__ kbuf,
              unsigned short* __restrict__ vtbuf) {
    const int sel = blockIdx.y;
    const int m0 = blockIdx.x * 128;
    const int t = threadIdx.x;
    const int lane = t & 63;
    const int w = t >> 6;
    const int wr = w >> 1;
    const int wc = w & 1;
    const int ln15 = lane & 15;
    const int g = lane >> 4;

    __shared__ __align__(16) unsigned short X0s[128][64];
    __shared__ __align__(16) unsigned short W0s[224][64];
    __shared__ __align__(16) unsigned short X1s[128][64];
    __shared__ __align__(16) unsigned short W1s[224][64];

    const unsigned short* wsel = wt + (size_t)sel * EP * KP;

    f32x4 acc[4][7];
#pragma unroll
    for (int i = 0; i < 4; ++i)
#pragma unroll
        for (int j = 0; j < 7; ++j) acc[i][j] = (f32x4)0.0f;

    const int rA = lane >> 3;
    const int cS = ((lane & 7) ^ rA) * 8;

    STAGE(X0s, W0s, 0);
    __syncthreads();
#pragma unroll
    for (int p = 0; p < 6; ++p) {
        STAGE(X1s, W1s, 2 * p + 1);
        COMPUTE(X0s, W0s);
        __syncthreads();
        STAGE(X0s, W0s, 2 * p + 2);
        COMPUTE(X1s, W1s);
        __syncthreads();
    }
    COMPUTE(X0s, W0s);

    // epilogue: gelu + store; V padding col 200 <- 1.0 (ones-column: PV
    // MFMA then computes softmax denominators for free in attn)
#pragma unroll
    for (int rf = 0; rf < 4; ++rf) {
        const int row = m0 + wr * 64 + rf * 16 + g * 4;
#pragma unroll
        for (int cf = 0; cf < 7; ++cf) {
            const int col = wc * 112 + cf * 16 + ln15;
            if (sel == 0) {
#pragma unroll
                for (int tt = 0; tt < 4; ++tt)
                    qbuf[(size_t)(row + tt) * EP + col] =
                        f2bf(gelu_fast(acc[rf][cf][tt]) * QSCL);
            } else if (sel == 1) {
#pragma unroll
                for (int tt = 0; tt < 4; ++tt)
                    kbuf[(size_t)(row + tt) * KSP + col] = f2bf(gelu_fast(acc[rf][cf][tt]));
            } else {
                const int bb = row >> 11, s = row & 2047;
                ushort4 pk;
                if (col == 200) {
                    pk.x = 0x3F80; pk.y = 0x3F80; pk.z = 0x3F80; pk.w = 0x3F80;
                } else {
                    pk.x = f2bf(gelu_fast(acc[rf][cf][0]));
                    pk.y = f2bf(gelu_fast(acc[rf][cf][1]));
                    pk.z = f2bf(gelu_fast(acc[rf][cf][2]));
                    pk.w = f2bf(gelu_fast(acc[rf][cf][3]));
                }
                *reinterpret_cast<ushort4*>(
                    &vtbuf[((size_t)(bb * EP + col)) * S_ + s]) = pk;
            }
        }
    }
}

// ---------------- Stage 2: flash attention ----------------
// BQ=128, 4 waves x 32 q-rows, BKV=64; grid 256 -> 1 block/CU.
// Double-buffered K/V (2-phase); no max-tracking (exp2-domain scores are
// provably small); denominators via V ones-column.
#define BQ  128
#define BKV 64

#define ASTAGE(KB, VB, KT) do {                                                  \
    const int kv0s = (KT) * BKV;                                                 \
    {                                                                            \
        const int r_in = lane >> 5;                                              \
        const int p = lane & 31;                                                 \
        _Pragma("unroll")                                                        \
        for (int i = 0; i < 8; ++i) {                                            \
            const int j = w * 8 + i;                                             \
            const int row = 2 * j + r_in;                                        \
            gload_lds16(kb_b + (size_t)(kv0s + row) * KSP + ((p ^ (row & 7)) * 8),\
                        &KB[j * 512]);                                           \
        }                                                                        \
    }                                                                            \
    {                                                                            \
        const int r_in = lane >> 3;                                              \
        const int p = lane & 7;                                                  \
        _Pragma("unroll")                                                        \
        for (int i = 0; i < 7; ++i) {                                            \
            const int j = w * 7 + i;                                             \
            const int row = 8 * j + r_in;                                        \
            gload_lds16(vt_b + (size_t)row * S_ + kv0s + ((p ^ (row & 7)) * 8),  \
                        &VB[j * 512]);                                           \
        }                                                                        \
    }                                                                            \
} while (0)

#define ACOMPUTE(KB, VB) do {                                                    \
    _Pragma("unroll")                                                            \
    for (int rf = 0; rf < 2; ++rf) {                                             \
        f32x4 sacc[4];                                                           \
        _Pragma("unroll")                                                        \
        for (int n = 0; n < 4; ++n) {                                            \
            f32x4 a = (f32x4)0.0f;                                               \
            const int krow = n * 16 + ln15;                                      \
            const unsigned short* kr = &KB[krow * KSP];                          \
            const int rx = krow & 7;                                             \
            _Pragma("unroll")                                                    \
            for (int s = 0; s < 7; ++s) {                                        \
                short8 bf = *reinterpret_cast<const short8*>(                    \
                    kr + (((s * 4 + g) ^ rx) * 8));                              \
                a = __builtin_amdgcn_mfma_f32_16x16x32_bf16(qf[rf][s], bf, a, 0, 0, 0); \
            }                                                                    \
            sacc[n] = a;                                                         \
        }                                                                        \
        _Pragma("unroll")                                                        \
        for (int n = 0; n < 4; ++n)                                              \
            _Pragma("unroll")                                                    \
            for (int tt = 0; tt < 4; ++tt)                                       \
                Plds[w][rf * 16 + g * 4 + tt][n * 16 + ln15] =                   \
                    f2bf(exp2_fast(sacc[n][tt]));                                \
    }                                                                            \
    short8 pf[2][2];                                                             \
    _Pragma("unroll")                                                            \
    for (int rf = 0; rf < 2; ++rf) {                                             \
        pf[rf][0] = *reinterpret_cast<const short8*>(&Plds[w][rf * 16 + ln15][g * 8]); \
        pf[rf][1] = *reinterpret_cast<const short8*>(&Plds[w][rf * 16 + ln15][32 + g * 8]); \
    }                                                                            \
    _Pragma("unroll")                                                            \
    for (int n = 0; n < 14; ++n) {                                               \
        const int vrow = n * 16 + ln15;                                          \
        const unsigned short* vr = &VB[vrow * 64];                               \
        const int rx = vrow & 7;                                                 \
        short8 b0 = *reinterpret_cast<const short8*>(vr + ((g ^ rx) * 8));       \
        short8 b1 = *reinterpret_cast<const short8*>(vr + (((4 + g) ^ rx) * 8)); \
        _Pragma("unroll")                                                        \
        for (int rf = 0; rf < 2; ++rf) {                                         \
            o[rf][n] = __builtin_amdgcn_mfma_f32_16x16x32_bf16(pf[rf][0], b0, o[rf][n], 0, 0, 0); \
            o[rf][n] = __builtin_amdgcn_mfma_f32_16x16x32_bf16(pf[rf][1], b1, o[rf][n], 0, 0, 0); \
        }                                                                        \
    }                                                                            \
} while (0)

__global__ __launch_bounds__(256, 1)
void attn_kernel(const unsigned short* __restrict__ qbuf,
                 const unsigned short* __restrict__ kbuf,
                 const unsigned short* __restrict__ vtbuf,
                 float* __restrict__ out) {
    // XCD-aware role remap: XCD c serves batches {2c, 2c+1} (K/V 3.6MB < 4MB L2)
    const int id = blockIdx.x;            // 0..255
    const int slot = id >> 3;             // 0..31
    const int b = 2 * (id & 7) + (slot >> 4);
    const int q0 = (slot & 15) * BQ;
    const int t = threadIdx.x;
    const int lane = t & 63;
    const int w = t >> 6;                 // 0..3
    const int ln15 = lane & 15;
    const int g = lane >> 4;              // 0..3

    __shared__ __align__(16) unsigned short Ks[2][BKV * KSP];   // 2 x 32KB
    __shared__ __align__(16) unsigned short Vts[2][EP * 64];    // 2 x 28KB
    __shared__ __align__(16) unsigned short Plds[4][32][68];    // 17KB

    // Q fragments: 32 rows per wave (pre-scaled by scale*log2e)
    short8 qf[2][7];
#pragma unroll
    for (int rf = 0; rf < 2; ++rf) {
        const unsigned short* qp =
            qbuf + (size_t)(b * S_ + q0 + w * 32 + rf * 16 + ln15) * EP + g * 8;
#pragma unroll
        for (int s = 0; s < 7; ++s)
            qf[rf][s] = *reinterpret_cast<const short8*>(qp + s * 32);
    }

    f32x4 o[2][14];
#pragma unroll
    for (int rf = 0; rf < 2; ++rf)
#pragma unroll
        for (int i = 0; i < 14; ++i) o[rf][i] = (f32x4)0.0f;

    const unsigned short* kb_b = kbuf + (size_t)b * S_ * KSP;
    const unsigned short* vt_b = vtbuf + (size_t)b * EP * S_;

    ASTAGE(Ks[0], Vts[0], 0);
    __syncthreads();
    for (int kt = 0; kt < S_ / BKV - 1; ++kt) {
        const int cur = kt & 1;
        ASTAGE(Ks[cur ^ 1], Vts[cur ^ 1], kt + 1);
        ACOMPUTE(Ks[cur], Vts[cur]);
        __syncthreads();
    }
    ACOMPUTE(Ks[1], Vts[1]);

    // epilogue: l = o[.][12] at col 200 (ln15==8); broadcast, normalize, store
#pragma unroll
    for (int rf = 0; rf < 2; ++rf) {
        float l[4];
#pragma unroll
        for (int tt = 0; tt < 4; ++tt)
            l[tt] = __shfl(o[rf][12][tt], (lane & 48) + 8, 64);
#pragma unroll
        for (int tt = 0; tt < 4; ++tt) {
            const float inv = 1.0f / l[tt];
            const int row = q0 + w * 32 + rf * 16 + g * 4 + tt;
            float* op = out + (size_t)(b * S_ + row) * E_;
#pragma unroll
            for (int n = 0; n < 13; ++n) {
                const int e = n * 16 + ln15;
                if (e < E_) op[e] = o[rf][n][tt] * inv;
            }
        }
    }
}

extern "C" void kernel_launch(void* const* d_in, const int* in_sizes, int n_in,
                              void* d_out, int out_size, void* d_ws, size_t ws_size,
                              hipStream_t stream) {
    const float* x  = (const float*)d_in[0];
    const float* Wq = (const float*)d_in[1];
    const float* Wk = (const float*)d_in[2];
    const float* Wv = (const float*)d_in[3];
    float* out = (float*)d_out;

    unsigned short* xb    = (unsigned short*)d_ws;                 // [M_][KP]
    unsigned short* wt    = xb + (size_t)M_ * KP;                  // [3][EP][KP]
    unsigned short* qbuf  = wt + (size_t)3 * EP * KP;              // [M_][EP]
    unsigned short* kbuf  = qbuf + (size_t)M_ * EP;                // [M_][KSP]
    unsigned short* vtbuf = kbuf + (size_t)M_ * KSP;               // [B_][EP][S_]

    prep_x<<<dim3(M_ * (KP / 8) / 256), 256, 0, stream>>>(x, xb);
    prep_w<<<dim3(3 * EP * KP / 256), 256, 0, stream>>>(Wq, Wk, Wv, wt);
    gemm_qkv<<<dim3(256, 3), 256, 0, stream>>>(xb, wt, qbuf, kbuf, vtbuf);
    attn_kernel<<<dim3(256), 256, 0, stream>>>(qbuf, kbuf, vtbuf, out);
}

// Round 7
// 188.501 us; speedup vs baseline: 2.4210x; 1.0846x over previous
//
#include <hip/hip_runtime.h>
#include <hip/hip_bf16.h>

#define B_  16
#define S_  2048
#define F_  800
#define E_  200
#define EP  224          // padded E (multiple of 32)
#define KP  832          // padded K (26 * 32)
#define KSP 256          // kbuf row pitch in shorts (32 x 16B slots, pow2 for swizzle)
#define M_  (B_ * S_)    // 32768

typedef __attribute__((ext_vector_type(8))) short short8;
typedef __attribute__((ext_vector_type(4))) float f32x4;

// scale = 1/sqrt(960); folded with log2(e) into Q so softmax runs in exp2 domain
#define QSCL (0.03227486121839514f * 1.4426950408889634f)

__device__ __forceinline__ unsigned short f2bf(float f) {
    __hip_bfloat16 h = __float2bfloat16(f);
    return *reinterpret_cast<unsigned short*>(&h);
}

__device__ __forceinline__ float exp2_fast(float x) {
    float r;
    asm("v_exp_f32 %0, %1" : "=v"(r) : "v"(x));
    return r;
}

__device__ __forceinline__ float rcp_fast(float x) {
    float r;
    asm("v_rcp_f32 %0, %1" : "=v"(r) : "v"(x));
    return r;
}

// tanh-form GELU (max |err| vs exact ~5e-4, below bf16 noise here)
__device__ __forceinline__ float gelu_fast(float x) {
    const float i = x + 0.044715f * x * x * x;
    const float z = 2.302265314f * i;              // 2*0.79788456*log2(e) * i
    return x * rcp_fast(1.0f + exp2_fast(-z));
}

__device__ __forceinline__ void gload_lds16(const void* g, void* l) {
    __builtin_amdgcn_global_load_lds(
        (const __attribute__((address_space(1))) unsigned int*)g,
        (__attribute__((address_space(3))) unsigned int*)l, 16, 0, 0);
}

// ---------------- prep: X fp32 -> bf16 padded [M][KP] ----------------
__global__ __launch_bounds__(256)
void prep_x(const float* __restrict__ x, unsigned short* __restrict__ xb) {
    const int id = blockIdx.x * 256 + threadIdx.x;
    const int r  = id / (KP / 8);
    const int c8 = id % (KP / 8);
    ushort4 lo = {0, 0, 0, 0}, hi = {0, 0, 0, 0};
    if (c8 < F_ / 8) {
        const float4 a = *reinterpret_cast<const float4*>(x + (size_t)r * F_ + c8 * 8);
        const float4 b = *reinterpret_cast<const float4*>(x + (size_t)r * F_ + c8 * 8 + 4);
        lo.x = f2bf(a.x); lo.y = f2bf(a.y); lo.z = f2bf(a.z); lo.w = f2bf(a.w);
        hi.x = f2bf(b.x); hi.y = f2bf(b.y); hi.z = f2bf(b.z); hi.w = f2bf(b.w);
    }
    unsigned short* dst = xb + (size_t)r * KP + c8 * 8;
    *reinterpret_cast<ushort4*>(dst) = lo;
    *reinterpret_cast<ushort4*>(dst + 4) = hi;
}

// ---------------- prep: W^T bf16 padded wt[3][EP][KP] ----------------
__global__ __launch_bounds__(256)
void prep_w(const float* __restrict__ Wq, const float* __restrict__ Wk,
            const float* __restrict__ Wv, unsigned short* __restrict__ wt) {
    const int id = blockIdx.x * 256 + threadIdx.x;
    const int sel = id / (EP * KP);
    const int rem = id % (EP * KP);
    const int e = rem / KP;
    const int k = rem % KP;
    const float* W = (sel == 0) ? Wq : ((sel == 1) ? Wk : Wv);
    float v = (e < E_ && k < F_) ? W[(size_t)k * E_ + e] : 0.0f;
    wt[id] = f2bf(v);
}

// ---------------- Stage 1 GEMM: Q/K/V = gelu(Xb @ W) ----------------
// BM=128, BN=224, BK=32; 4 waves (2M x 2N); LDS 44KB -> 2 blocks/CU.
// Tiles stored with granule swizzle phys = logical ^ (row & 3) (64B rows).
#define STAGE(XB, WB, KK) do {                                                   \
    const int k0s = (KK) * 32;                                                   \
    _Pragma("unroll")                                                            \
    for (int i = 0; i < 2; ++i) {                                                \
        const int j = w * 2 + i;                                                 \
        const int row = 16 * j + rS;                                             \
        gload_lds16(xb + (size_t)(m0 + row) * KP + k0s + ((pS ^ (row & 3)) * 8), \
                    &XB[j * 512]);                                               \
    }                                                                            \
    _Pragma("unroll")                                                            \
    for (int i = 0; i < 4; ++i) {                                                \
        const int j = i * 4 + w;                                                 \
        if (j < 14) {                                                            \
            const int row = 16 * j + rS;                                         \
            gload_lds16(wsel + (size_t)row * KP + k0s + ((pS ^ (row & 3)) * 8),  \
                        &WB[j * 512]);                                           \
        }                                                                        \
    }                                                                            \
} while (0)

#define COMPUTE(XB, WB) do {                                                     \
    short8 afr[4];                                                               \
    _Pragma("unroll")                                                            \
    for (int rf = 0; rf < 4; ++rf) {                                             \
        const int row = wr * 64 + rf * 16 + ln15;                                \
        afr[rf] = *reinterpret_cast<const short8*>(                              \
            &XB[row * 32 + ((g ^ (row & 3)) * 8)]);                              \
    }                                                                            \
    _Pragma("unroll")                                                            \
    for (int cf = 0; cf < 7; ++cf) {                                             \
        const int row = wc * 112 + cf * 16 + ln15;                               \
        short8 bfr = *reinterpret_cast<const short8*>(                           \
            &WB[row * 32 + ((g ^ (row & 3)) * 8)]);                              \
        _Pragma("unroll")                                                        \
        for (int rf = 0; rf < 4; ++rf)                                           \
            acc[rf][cf] = __builtin_amdgcn_mfma_f32_16x16x32_bf16(               \
                afr[rf], bfr, acc[rf][cf], 0, 0, 0);                             \
    }                                                                            \
} while (0)

__global__ __launch_bounds__(256, 2)
void gemm_qkv(const unsigned short* __restrict__ xb,
              const unsigned short* __restrict__ wt,
              unsigned short* __restrict__ qbuf,
              unsigned short* __restrict__ kbuf,
              unsigned short* __restrict__ vtbuf) {
    const int sel = blockIdx.y;
    const int m0 = blockIdx.x * 128;
    const int t = threadIdx.x;
    const int lane = t & 63;
    const int w = t >> 6;
    const int wr = w >> 1;
    const int wc = w & 1;
    const int ln15 = lane & 15;
    const int g = lane >> 4;

    __shared__ __align__(16) unsigned short X0s[128 * 32];
    __shared__ __align__(16) unsigned short W0s[224 * 32];
    __shared__ __align__(16) unsigned short X1s[128 * 32];
    __shared__ __align__(16) unsigned short W1s[224 * 32];

    const unsigned short* wsel = wt + (size_t)sel * EP * KP;

    f32x4 acc[4][7];
#pragma unroll
    for (int i = 0; i < 4; ++i)
#pragma unroll
        for (int j = 0; j < 7; ++j) acc[i][j] = (f32x4)0.0f;

    const int rS = lane >> 2;            // staging row within 16-row chunk
    const int pS = lane & 3;             // staging physical granule

    STAGE(X0s, W0s, 0);
    __syncthreads();
#pragma unroll
    for (int p = 0; p < 12; ++p) {
        STAGE(X1s, W1s, 2 * p + 1);
        COMPUTE(X0s, W0s);
        __syncthreads();
        STAGE(X0s, W0s, 2 * p + 2);
        COMPUTE(X1s, W1s);
        __syncthreads();
    }
    STAGE(X1s, W1s, 25);
    COMPUTE(X0s, W0s);                   // kk = 24
    __syncthreads();
    COMPUTE(X1s, W1s);                   // kk = 25

    // epilogue: gelu + store; V padding col 200 <- 1.0 (ones-column: PV
    // MFMA computes softmax denominators for free in attn)
#pragma unroll
    for (int rf = 0; rf < 4; ++rf) {
        const int row = m0 + wr * 64 + rf * 16 + g * 4;
#pragma unroll
        for (int cf = 0; cf < 7; ++cf) {
            const int col = wc * 112 + cf * 16 + ln15;
            if (sel == 0) {
#pragma unroll
                for (int tt = 0; tt < 4; ++tt)
                    qbuf[(size_t)(row + tt) * EP + col] =
                        f2bf(gelu_fast(acc[rf][cf][tt]) * QSCL);
            } else if (sel == 1) {
#pragma unroll
                for (int tt = 0; tt < 4; ++tt)
                    kbuf[(size_t)(row + tt) * KSP + col] = f2bf(gelu_fast(acc[rf][cf][tt]));
            } else {
                const int bb = row >> 11, s = row & 2047;
                ushort4 pk;
                if (col == 200) {
                    pk.x = 0x3F80; pk.y = 0x3F80; pk.z = 0x3F80; pk.w = 0x3F80;
                } else {
                    pk.x = f2bf(gelu_fast(acc[rf][cf][0]));
                    pk.y = f2bf(gelu_fast(acc[rf][cf][1]));
                    pk.z = f2bf(gelu_fast(acc[rf][cf][2]));
                    pk.w = f2bf(gelu_fast(acc[rf][cf][3]));
                }
                *reinterpret_cast<ushort4*>(
                    &vtbuf[((size_t)(bb * EP + col)) * S_ + s]) = pk;
            }
        }
    }
}

// ---------------- Stage 2: flash attention (round-5 verbatim) ----------------
// BQ=128, 4 waves x 32 q-rows, BKV=64 double-buffered; grid 256 -> 1 block/CU.
#define BQ  128
#define BKV 64

#define ASTAGE(KB, VB, KT) do {                                                  \
    const int kv0s = (KT) * BKV;                                                 \
    {                                                                            \
        const int r_in = lane >> 5;                                              \
        const int p = lane & 31;                                                 \
        _Pragma("unroll")                                                        \
        for (int i = 0; i < 8; ++i) {                                            \
            const int j = w * 8 + i;                                             \
            const int row = 2 * j + r_in;                                        \
            gload_lds16(kb_b + (size_t)(kv0s + row) * KSP + ((p ^ (row & 7)) * 8),\
                        &KB[j * 512]);                                           \
        }                                                                        \
    }                                                                            \
    {                                                                            \
        const int r_in = lane >> 3;                                              \
        const int p = lane & 7;                                                  \
        _Pragma("unroll")                                                        \
        for (int i = 0; i < 7; ++i) {                                            \
            const int j = w * 7 + i;                                             \
            const int row = 8 * j + r_in;                                        \
            gload_lds16(vt_b + (size_t)row * S_ + kv0s + ((p ^ (row & 7)) * 8),  \
                        &VB[j * 512]);                                           \
        }                                                                        \
    }                                                                            \
} while (0)

#define ACOMPUTE(KB, VB) do {                                                    \
    _Pragma("unroll")                                                            \
    for (int rf = 0; rf < 2; ++rf) {                                             \
        f32x4 sacc[4];                                                           \
        _Pragma("unroll")                                                        \
        for (int n = 0; n < 4; ++n) {                                            \
            f32x4 a = (f32x4)0.0f;                                               \
            const int krow = n * 16 + ln15;                                      \
            const unsigned short* kr = &KB[krow * KSP];                          \
            const int rx = krow & 7;                                             \
            _Pragma("unroll")                                                    \
            for (int s = 0; s < 7; ++s) {                                        \
                short8 bf = *reinterpret_cast<const short8*>(                    \
                    kr + (((s * 4 + g) ^ rx) * 8));                              \
                a = __builtin_amdgcn_mfma_f32_16x16x32_bf16(qf[rf][s], bf, a, 0, 0, 0); \
            }                                                                    \
            sacc[n] = a;                                                         \
        }                                                                        \
        _Pragma("unroll")                                                        \
        for (int n = 0; n < 4; ++n)                                              \
            _Pragma("unroll")                                                    \
            for (int tt = 0; tt < 4; ++tt)                                       \
                Plds[w][rf * 16 + g * 4 + tt][n * 16 + ln15] =                   \
                    f2bf(exp2_fast(sacc[n][tt]));                                \
    }                                                                            \
    short8 pf[2][2];                                                             \
    _Pragma("unroll")                                                            \
    for (int rf = 0; rf < 2; ++rf) {                                             \
        pf[rf][0] = *reinterpret_cast<const short8*>(&Plds[w][rf * 16 + ln15][g * 8]); \
        pf[rf][1] = *reinterpret_cast<const short8*>(&Plds[w][rf * 16 + ln15][32 + g * 8]); \
    }                                                                            \
    _Pragma("unroll")                                                            \
    for (int n = 0; n < 14; ++n) {                                               \
        const int vrow = n * 16 + ln15;                                          \
        const unsigned short* vr = &VB[vrow * 64];                               \
        const int rx = vrow & 7;                                                 \
        short8 b0 = *reinterpret_cast<const short8*>(vr + ((g ^ rx) * 8));       \
        short8 b1 = *reinterpret_cast<const short8*>(vr + (((4 + g) ^ rx) * 8)); \
        _Pragma("unroll")                                                        \
        for (int rf = 0; rf < 2; ++rf) {                                         \
            o[rf][n] = __builtin_amdgcn_mfma_f32_16x16x32_bf16(pf[rf][0], b0, o[rf][n], 0, 0, 0); \
            o[rf][n] = __builtin_amdgcn_mfma_f32_16x16x32_bf16(pf[rf][1], b1, o[rf][n], 0, 0, 0); \
        }                                                                        \
    }                                                                            \
} while (0)

__global__ __launch_bounds__(256, 1)
void attn_kernel(const unsigned short* __restrict__ qbuf,
                 const unsigned short* __restrict__ kbuf,
                 const unsigned short* __restrict__ vtbuf,
                 float* __restrict__ out) {
    // XCD-aware role remap: XCD c serves batches {2c, 2c+1} (K/V 3.6MB < 4MB L2)
    const int id = blockIdx.x;            // 0..255
    const int slot = id >> 3;             // 0..31
    const int b = 2 * (id & 7) + (slot >> 4);
    const int q0 = (slot & 15) * BQ;
    const int t = threadIdx.x;
    const int lane = t & 63;
    const int w = t >> 6;                 // 0..3
    const int ln15 = lane & 15;
    const int g = lane >> 4;              // 0..3

    __shared__ __align__(16) unsigned short Ks[2][BKV * KSP];   // 2 x 32KB
    __shared__ __align__(16) unsigned short Vts[2][EP * 64];    // 2 x 28KB
    __shared__ __align__(16) unsigned short Plds[4][32][68];    // 17KB

    // Q fragments: 32 rows per wave (pre-scaled by scale*log2e)
    short8 qf[2][7];
#pragma unroll
    for (int rf = 0; rf < 2; ++rf) {
        const unsigned short* qp =
            qbuf + (size_t)(b * S_ + q0 + w * 32 + rf * 16 + ln15) * EP + g * 8;
#pragma unroll
        for (int s = 0; s < 7; ++s)
            qf[rf][s] = *reinterpret_cast<const short8*>(qp + s * 32);
    }

    f32x4 o[2][14];
#pragma unroll
    for (int rf = 0; rf < 2; ++rf)
#pragma unroll
        for (int i = 0; i < 14; ++i) o[rf][i] = (f32x4)0.0f;

    const unsigned short* kb_b = kbuf + (size_t)b * S_ * KSP;
    const unsigned short* vt_b = vtbuf + (size_t)b * EP * S_;

    ASTAGE(Ks[0], Vts[0], 0);
    __syncthreads();
    for (int kt = 0; kt < S_ / BKV - 1; ++kt) {
        const int cur = kt & 1;
        ASTAGE(Ks[cur ^ 1], Vts[cur ^ 1], kt + 1);
        ACOMPUTE(Ks[cur], Vts[cur]);
        __syncthreads();
    }
    ACOMPUTE(Ks[1], Vts[1]);

    // epilogue: l = o[.][12] at col 200 (ln15==8); broadcast, normalize, store
#pragma unroll
    for (int rf = 0; rf < 2; ++rf) {
        float l[4];
#pragma unroll
        for (int tt = 0; tt < 4; ++tt)
            l[tt] = __shfl(o[rf][12][tt], (lane & 48) + 8, 64);
#pragma unroll
        for (int tt = 0; tt < 4; ++tt) {
            const float inv = 1.0f / l[tt];
            const int row = q0 + w * 32 + rf * 16 + g * 4 + tt;
            float* op = out + (size_t)(b * S_ + row) * E_;
#pragma unroll
            for (int n = 0; n < 13; ++n) {
                const int e = n * 16 + ln15;
                if (e < E_) op[e] = o[rf][n][tt] * inv;
            }
        }
    }
}

extern "C" void kernel_launch(void* const* d_in, const int* in_sizes, int n_in,
                              void* d_out, int out_size, void* d_ws, size_t ws_size,
                              hipStream_t stream) {
    const float* x  = (const float*)d_in[0];
    const float* Wq = (const float*)d_in[1];
    const float* Wk = (const float*)d_in[2];
    const float* Wv = (const float*)d_in[3];
    float* out = (float*)d_out;

    unsigned short* xb    = (unsigned short*)d_ws;                 // [M_][KP]
    unsigned short* wt    = xb + (size_t)M_ * KP;                  // [3][EP][KP]
    unsigned short* qbuf  = wt + (size_t)3 * EP * KP;              // [M_][EP]
    unsigned short* kbuf  = qbuf + (size_t)M_ * EP;                // [M_][KSP]
    unsigned short* vtbuf = kbuf + (size_t)M_ * KSP;               // [B_][EP][S_]

    prep_x<<<dim3(M_ * (KP / 8) / 256), 256, 0, stream>>>(x, xb);
    prep_w<<<dim3(3 * EP * KP / 256), 256, 0, stream>>>(Wq, Wk, Wv, wt);
    gemm_qkv<<<dim3(256, 3), 256, 0, stream>>>(xb, wt, qbuf, kbuf, vtbuf);
    attn_kernel<<<dim3(256), 256, 0, stream>>>(qbuf, kbuf, vtbuf, out);
}

// Round 13
// 188.380 us; speedup vs baseline: 2.4226x; 1.0006x over previous
//
#include <hip/hip_runtime.h>
#include <hip/hip_bf16.h>

#define B_  16
#define S_  2048
#define F_  800
#define E_  200
#define EP  224          // padded E (multiple of 32)
#define KP  832          // padded K (26 * 32)
#define KSP 256          // kbuf row pitch in shorts (32 x 16B slots, pow2 for swizzle)
#define M_  (B_ * S_)    // 32768

typedef __attribute__((ext_vector_type(8))) short short8;
typedef __attribute__((ext_vector_type(4))) float f32x4;

// scale = 1/sqrt(960); folded with log2(e) into Q so softmax runs in exp2 domain
#define QSCL (0.03227486121839514f * 1.4426950408889634f)

__device__ __forceinline__ unsigned short f2bf(float f) {
    __hip_bfloat16 h = __float2bfloat16(f);
    return *reinterpret_cast<unsigned short*>(&h);
}

__device__ __forceinline__ float exp2_fast(float x) {
    float r;
    asm("v_exp_f32 %0, %1" : "=v"(r) : "v"(x));
    return r;
}

__device__ __forceinline__ float rcp_fast(float x) {
    float r;
    asm("v_rcp_f32 %0, %1" : "=v"(r) : "v"(x));
    return r;
}

// tanh-form GELU (max |err| vs exact ~5e-4, below bf16 noise here)
__device__ __forceinline__ float gelu_fast(float x) {
    const float i = x + 0.044715f * x * x * x;
    const float z = 2.302265314f * i;              // 2*0.79788456*log2(e) * i
    return x * rcp_fast(1.0f + exp2_fast(-z));
}

__device__ __forceinline__ void gload_lds16(const void* g, void* l) {
    __builtin_amdgcn_global_load_lds(
        (const __attribute__((address_space(1))) unsigned int*)g,
        (__attribute__((address_space(3))) unsigned int*)l, 16, 0, 0);
}

// ---------------- prep: X fp32 -> bf16 padded [M][KP] ----------------
__global__ __launch_bounds__(256)
void prep_x(const float* __restrict__ x, unsigned short* __restrict__ xb) {
    const int id = blockIdx.x * 256 + threadIdx.x;
    const int r  = id / (KP / 8);
    const int c8 = id % (KP / 8);
    ushort4 lo = {0, 0, 0, 0}, hi = {0, 0, 0, 0};
    if (c8 < F_ / 8) {
        const float4 a = *reinterpret_cast<const float4*>(x + (size_t)r * F_ + c8 * 8);
        const float4 b = *reinterpret_cast<const float4*>(x + (size_t)r * F_ + c8 * 8 + 4);
        lo.x = f2bf(a.x); lo.y = f2bf(a.y); lo.z = f2bf(a.z); lo.w = f2bf(a.w);
        hi.x = f2bf(b.x); hi.y = f2bf(b.y); hi.z = f2bf(b.z); hi.w = f2bf(b.w);
    }
    unsigned short* dst = xb + (size_t)r * KP + c8 * 8;
    *reinterpret_cast<ushort4*>(dst) = lo;
    *reinterpret_cast<ushort4*>(dst + 4) = hi;
}

// ---------------- prep: W^T bf16 padded wt[3][EP][KP] ----------------
__global__ __launch_bounds__(256)
void prep_w(const float* __restrict__ Wq, const float* __restrict__ Wk,
            const float* __restrict__ Wv, unsigned short* __restrict__ wt) {
    const int id = blockIdx.x * 256 + threadIdx.x;
    const int sel = id / (EP * KP);
    const int rem = id % (EP * KP);
    const int e = rem / KP;
    const int k = rem % KP;
    const float* W = (sel == 0) ? Wq : ((sel == 1) ? Wk : Wv);
    float v = (e < E_ && k < F_) ? W[(size_t)k * E_ + e] : 0.0f;
    wt[id] = f2bf(v);
}

// ---------------- Stage 1 GEMM: Q/K/V = gelu(Xb @ W) ----------------
// BM=128, BN=224, BK=32; 4 waves (2M x 2N); LDS 44KB -> 2 blocks/CU.
// Tiles stored with granule swizzle phys = logical ^ (row & 3) (64B rows).
#define STAGE(XB, WB, KK) do {                                                   \
    const int k0s = (KK) * 32;                                                   \
    _Pragma("unroll")                                                            \
    for (int i = 0; i < 2; ++i) {                                                \
        const int j = w * 2 + i;                                                 \
        const int row = 16 * j + rS;                                             \
        gload_lds16(xb + (size_t)(m0 + row) * KP + k0s + ((pS ^ (row & 3)) * 8), \
                    &XB[j * 512]);                                               \
    }                                                                            \
    _Pragma("unroll")                                                            \
    for (int i = 0; i < 4; ++i) {                                                \
        const int j = i * 4 + w;                                                 \
        if (j < 14) {                                                            \
            const int row = 16 * j + rS;                                         \
            gload_lds16(wsel + (size_t)row * KP + k0s + ((pS ^ (row & 3)) * 8),  \
                        &WB[j * 512]);                                           \
        }                                                                        \
    }                                                                            \
} while (0)

#define COMPUTE(XB, WB) do {                                                     \
    short8 afr[4];                                                               \
    _Pragma("unroll")                                                            \
    for (int rf = 0; rf < 4; ++rf) {                                             \
        const int row = wr * 64 + rf * 16 + ln15;                                \
        afr[rf] = *reinterpret_cast<const short8*>(                              \
            &XB[row * 32 + ((g ^ (row & 3)) * 8)]);                              \
    }                                                                            \
    _Pragma("unroll")                                                            \
    for (int cf = 0; cf < 7; ++cf) {                                             \
        const int row = wc * 112 + cf * 16 + ln15;                               \
        short8 bfr = *reinterpret_cast<const short8*>(                           \
            &WB[row * 32 + ((g ^ (row & 3)) * 8)]);                              \
        _Pragma("unroll")                                                        \
        for (int rf = 0; rf < 4; ++rf)                                           \
            acc[rf][cf] = __builtin_amdgcn_mfma_f32_16x16x32_bf16(               \
                afr[rf], bfr, acc[rf][cf], 0, 0, 0);                             \
    }                                                                            \
} while (0)

__global__ __launch_bounds__(256, 2)
void gemm_qkv(const unsigned short* __restrict__ xb,
              const unsigned short* __restrict__ wt,
              unsigned short* __restrict__ qbuf,
              unsigned short* __restrict__ kbuf,
              unsigned short* __restrict__ vtbuf) {
    const int sel = blockIdx.y;
    const int m0 = blockIdx.x * 128;
    const int t = threadIdx.x;
    const int lane = t & 63;
    const int w = t >> 6;
    const int wr = w >> 1;
    const int wc = w & 1;
    const int ln15 = lane & 15;
    const int g = lane >> 4;

    __shared__ __align__(16) unsigned short X0s[128 * 32];
    __shared__ __align__(16) unsigned short W0s[224 * 32];
    __shared__ __align__(16) unsigned short X1s[128 * 32];
    __shared__ __align__(16) unsigned short W1s[224 * 32];

    const unsigned short* wsel = wt + (size_t)sel * EP * KP;

    f32x4 acc[4][7];
#pragma unroll
    for (int i = 0; i < 4; ++i)
#pragma unroll
        for (int j = 0; j < 7; ++j) acc[i][j] = (f32x4)0.0f;

    const int rS = lane >> 2;            // staging row within 16-row chunk
    const int pS = lane & 3;             // staging physical granule

    STAGE(X0s, W0s, 0);
    __syncthreads();
#pragma unroll
    for (int p = 0; p < 12; ++p) {
        STAGE(X1s, W1s, 2 * p + 1);
        COMPUTE(X0s, W0s);
        __syncthreads();
        STAGE(X0s, W0s, 2 * p + 2);
        COMPUTE(X1s, W1s);
        __syncthreads();
    }
    STAGE(X1s, W1s, 25);
    COMPUTE(X0s, W0s);                   // kk = 24
    __syncthreads();
    COMPUTE(X1s, W1s);                   // kk = 25

    // epilogue: gelu + store; V padding col 200 <- 1.0 (ones-column: PV
    // MFMA computes softmax denominators for free in attn)
#pragma unroll
    for (int rf = 0; rf < 4; ++rf) {
        const int row = m0 + wr * 64 + rf * 16 + g * 4;
#pragma unroll
        for (int cf = 0; cf < 7; ++cf) {
            const int col = wc * 112 + cf * 16 + ln15;
            if (sel == 0) {
#pragma unroll
                for (int tt = 0; tt < 4; ++tt)
                    qbuf[(size_t)(row + tt) * EP + col] =
                        f2bf(gelu_fast(acc[rf][cf][tt]) * QSCL);
            } else if (sel == 1) {
#pragma unroll
                for (int tt = 0; tt < 4; ++tt)
                    kbuf[(size_t)(row + tt) * KSP + col] = f2bf(gelu_fast(acc[rf][cf][tt]));
            } else {
                const int bb = row >> 11, s = row & 2047;
                ushort4 pk;
                if (col == 200) {
                    pk.x = 0x3F80; pk.y = 0x3F80; pk.z = 0x3F80; pk.w = 0x3F80;
                } else {
                    pk.x = f2bf(gelu_fast(acc[rf][cf][0]));
                    pk.y = f2bf(gelu_fast(acc[rf][cf][1]));
                    pk.z = f2bf(gelu_fast(acc[rf][cf][2]));
                    pk.w = f2bf(gelu_fast(acc[rf][cf][3]));
                }
                *reinterpret_cast<ushort4*>(
                    &vtbuf[((size_t)(bb * EP + col)) * S_ + s]) = pk;
            }
        }
    }
}

// ---------------- Stage 2: flash attention (round-5 verbatim) ----------------
// BQ=128, 4 waves x 32 q-rows, BKV=64 double-buffered; grid 256 -> 1 block/CU.
#define BQ  128
#define BKV 64

#define ASTAGE(KB, VB, KT) do {                                                  \
    const int kv0s = (KT) * BKV;                                                 \
    {                                                                            \
        const int r_in = lane >> 5;                                              \
        const int p = lane & 31;                                                 \
        _Pragma("unroll")                                                        \
        for (int i = 0; i < 8; ++i) {                                            \
            const int j = w * 8 + i;                                             \
            const int row = 2 * j + r_in;                                        \
            gload_lds16(kb_b + (size_t)(kv0s + row) * KSP + ((p ^ (row & 7)) * 8),\
                        &KB[j * 512]);                                           \
        }                                                                        \
    }                                                                            \
    {                                                                            \
        const int r_in = lane >> 3;                                              \
        const int p = lane & 7;                                                  \
        _Pragma("unroll")                                                        \
        for (int i = 0; i < 7; ++i) {                                            \
            const int j = w * 7 + i;                                             \
            const int row = 8 * j + r_in;                                        \
            gload_lds16(vt_b + (size_t)row * S_ + kv0s + ((p ^ (row & 7)) * 8),  \
                        &VB[j * 512]);                                           \
        }                                                                        \
    }                                                                            \
} while (0)

#define ACOMPUTE(KB, VB) do {                                                    \
    _Pragma("unroll")                                                            \
    for (int rf = 0; rf < 2; ++rf) {                                             \
        f32x4 sacc[4];                                                           \
        _Pragma("unroll")                                                        \
        for (int n = 0; n < 4; ++n) {                                            \
            f32x4 a = (f32x4)0.0f;                                               \
            const int krow = n * 16 + ln15;                                      \
            const unsigned short* kr = &KB[krow * KSP];                          \
            const int rx = krow & 7;                                             \
            _Pragma("unroll")                                                    \
            for (int s = 0; s < 7; ++s) {                                        \
                short8 bf = *reinterpret_cast<const short8*>(                    \
                    kr + (((s * 4 + g) ^ rx) * 8));                              \
                a = __builtin_amdgcn_mfma_f32_16x16x32_bf16(qf[rf][s], bf, a, 0, 0, 0); \
            }                                                                    \
            sacc[n] = a;                                                         \
        }                                                                        \
        _Pragma("unroll")                                                        \
        for (int n = 0; n < 4; ++n)                                              \
            _Pragma("unroll")                                                    \
            for (int tt = 0; tt < 4; ++tt)                                       \
                Plds[w][rf * 16 + g * 4 + tt][n * 16 + ln15] =                   \
                    f2bf(exp2_fast(sacc[n][tt]));                                \
    }                                                                            \
    short8 pf[2][2];                                                             \
    _Pragma("unroll")                                                            \
    for (int rf = 0; rf < 2; ++rf) {                                             \
        pf[rf][0] = *reinterpret_cast<const short8*>(&Plds[w][rf * 16 + ln15][g * 8]); \
        pf[rf][1] = *reinterpret_cast<const short8*>(&Plds[w][rf * 16 + ln15][32 + g * 8]); \
    }                                                                            \
    _Pragma("unroll")                                                            \
    for (int n = 0; n < 14; ++n) {                                               \
        const int vrow = n * 16 + ln15;                                          \
        const unsigned short* vr = &VB[vrow * 64];                               \
        const int rx = vrow & 7;                                                 \
        short8 b0 = *reinterpret_cast<const short8*>(vr + ((g ^ rx) * 8));       \
        short8 b1 = *reinterpret_cast<const short8*>(vr + (((4 + g) ^ rx) * 8)); \
        _Pragma("unroll")                                                        \
        for (int rf = 0; rf < 2; ++rf) {                                         \
            o[rf][n] = __builtin_amdgcn_mfma_f32_16x16x32_bf16(pf[rf][0], b0, o[rf][n], 0, 0, 0); \
            o[rf][n] = __builtin_amdgcn_mfma_f32_16x16x32_bf16(pf[rf][1], b1, o[rf][n], 0, 0, 0); \
        }                                                                        \
    }                                                                            \
} while (0)

__global__ __launch_bounds__(256, 1)
void attn_kernel(const unsigned short* __restrict__ qbuf,
                 const unsigned short* __restrict__ kbuf,
                 const unsigned short* __restrict__ vtbuf,
                 float* __restrict__ out) {
    // XCD-aware role remap: XCD c serves batches {2c, 2c+1} (K/V 3.6MB < 4MB L2)
    const int id = blockIdx.x;            // 0..255
    const int slot = id >> 3;             // 0..31
    const int b = 2 * (id & 7) + (slot >> 4);
    const int q0 = (slot & 15) * BQ;
    const int t = threadIdx.x;
    const int lane = t & 63;
    const int w = t >> 6;                 // 0..3
    const int ln15 = lane & 15;
    const int g = lane >> 4;              // 0..3

    __shared__ __align__(16) unsigned short Ks[2][BKV * KSP];   // 2 x 32KB
    __shared__ __align__(16) unsigned short Vts[2][EP * 64];    // 2 x 28KB
    __shared__ __align__(16) unsigned short Plds[4][32][68];    // 17KB

    // Q fragments: 32 rows per wave (pre-scaled by scale*log2e)
    short8 qf[2][7];
#pragma unroll
    for (int rf = 0; rf < 2; ++rf) {
        const unsigned short* qp =
            qbuf + (size_t)(b * S_ + q0 + w * 32 + rf * 16 + ln15) * EP + g * 8;
#pragma unroll
        for (int s = 0; s < 7; ++s)
            qf[rf][s] = *reinterpret_cast<const short8*>(qp + s * 32);
    }

    f32x4 o[2][14];
#pragma unroll
    for (int rf = 0; rf < 2; ++rf)
#pragma unroll
        for (int i = 0; i < 14; ++i) o[rf][i] = (f32x4)0.0f;

    const unsigned short* kb_b = kbuf + (size_t)b * S_ * KSP;
    const unsigned short* vt_b = vtbuf + (size_t)b * EP * S_;

    ASTAGE(Ks[0], Vts[0], 0);
    __syncthreads();
    for (int kt = 0; kt < S_ / BKV - 1; ++kt) {
        const int cur = kt & 1;
        ASTAGE(Ks[cur ^ 1], Vts[cur ^ 1], kt + 1);
        ACOMPUTE(Ks[cur], Vts[cur]);
        __syncthreads();
    }
    ACOMPUTE(Ks[1], Vts[1]);

    // epilogue: l = o[.][12] at col 200 (ln15==8); broadcast, normalize, store
#pragma unroll
    for (int rf = 0; rf < 2; ++rf) {
        float l[4];
#pragma unroll
        for (int tt = 0; tt < 4; ++tt)
            l[tt] = __shfl(o[rf][12][tt], (lane & 48) + 8, 64);
#pragma unroll
        for (int tt = 0; tt < 4; ++tt) {
            const float inv = 1.0f / l[tt];
            const int row = q0 + w * 32 + rf * 16 + g * 4 + tt;
            float* op = out + (size_t)(b * S_ + row) * E_;
#pragma unroll
            for (int n = 0; n < 13; ++n) {
                const int e = n * 16 + ln15;
                if (e < E_) op[e] = o[rf][n][tt] * inv;
            }
        }
    }
}

extern "C" void kernel_launch(void* const* d_in, const int* in_sizes, int n_in,
                              void* d_out, int out_size, void* d_ws, size_t ws_size,
                              hipStream_t stream) {
    const float* x  = (const float*)d_in[0];
    const float* Wq = (const float*)d_in[1];
    const float* Wk = (const float*)d_in[2];
    const float* Wv = (const float*)d_in[3];
    float* out = (float*)d_out;

    unsigned short* xb    = (unsigned short*)d_ws;                 // [M_][KP]
    unsigned short* wt    = xb + (size_t)M_ * KP;                  // [3][EP][KP]
    unsigned short* qbuf  = wt + (size_t)3 * EP * KP;              // [M_][EP]
    unsigned short* kbuf  = qbuf + (size_t)M_ * EP;                // [M_][KSP]
    unsigned short* vtbuf = kbuf + (size_t)M_ * KSP;               // [B_][EP][S_]

    prep_x<<<dim3(M_ * (KP / 8) / 256), 256, 0, stream>>>(x, xb);
    prep_w<<<dim3(3 * EP * KP / 256), 256, 0, stream>>>(Wq, Wk, Wv, wt);
    gemm_qkv<<<dim3(256, 3), 256, 0, stream>>>(xb, wt, qbuf, kbuf, vtbuf);
    attn_kernel<<<dim3(256), 256, 0, stream>>>(qbuf, kbuf, vtbuf, out);
}

// Round 15
// 169.980 us; speedup vs baseline: 2.6848x; 1.1083x over previous
//
#include <hip/hip_runtime.h>
#include <hip/hip_bf16.h>

#define B_  16
#define S_  2048
#define F_  800
#define E_  200
#define EP  224          // padded E (multiple of 32)
#define KP  832          // padded K (26 * 32)
#define KSP 256          // kbuf row pitch in shorts (32 x 16B slots, pow2 for swizzle)
#define M_  (B_ * S_)    // 32768

typedef __attribute__((ext_vector_type(8))) short short8;
typedef __attribute__((ext_vector_type(4))) float f32x4;

// scale = 1/sqrt(960); folded with log2(e) into Q so softmax runs in exp2 domain
#define QSCL (0.03227486121839514f * 1.4426950408889634f)

__device__ __forceinline__ unsigned short f2bf(float f) {
    __hip_bfloat16 h = __float2bfloat16(f);
    return *reinterpret_cast<unsigned short*>(&h);
}

__device__ __forceinline__ float exp2_fast(float x) {
    float r;
    asm("v_exp_f32 %0, %1" : "=v"(r) : "v"(x));
    return r;
}

__device__ __forceinline__ float rcp_fast(float x) {
    float r;
    asm("v_rcp_f32 %0, %1" : "=v"(r) : "v"(x));
    return r;
}

// tanh-form GELU (max |err| vs exact ~5e-4, below bf16 noise here)
__device__ __forceinline__ float gelu_fast(float x) {
    const float i = x + 0.044715f * x * x * x;
    const float z = 2.302265314f * i;              // 2*0.79788456*log2(e) * i
    return x * rcp_fast(1.0f + exp2_fast(-z));
}

__device__ __forceinline__ void gload_lds16(const void* g, void* l) {
    __builtin_amdgcn_global_load_lds(
        (const __attribute__((address_space(1))) unsigned int*)g,
        (__attribute__((address_space(3))) unsigned int*)l, 16, 0, 0);
}

// ---------------- prep: X fp32 -> bf16 padded [M][KP] ----------------
__global__ __launch_bounds__(256)
void prep_x(const float* __restrict__ x, unsigned short* __restrict__ xb) {
    const int id = blockIdx.x * 256 + threadIdx.x;
    const int r  = id / (KP / 8);
    const int c8 = id % (KP / 8);
    ushort4 lo = {0, 0, 0, 0}, hi = {0, 0, 0, 0};
    if (c8 < F_ / 8) {
        const float4 a = *reinterpret_cast<const float4*>(x + (size_t)r * F_ + c8 * 8);
        const float4 b = *reinterpret_cast<const float4*>(x + (size_t)r * F_ + c8 * 8 + 4);
        lo.x = f2bf(a.x); lo.y = f2bf(a.y); lo.z = f2bf(a.z); lo.w = f2bf(a.w);
        hi.x = f2bf(b.x); hi.y = f2bf(b.y); hi.z = f2bf(b.z); hi.w = f2bf(b.w);
    }
    unsigned short* dst = xb + (size_t)r * KP + c8 * 8;
    *reinterpret_cast<ushort4*>(dst) = lo;
    *reinterpret_cast<ushort4*>(dst + 4) = hi;
}

// ---------------- prep: W^T bf16 padded wt[3][EP][KP] ----------------
__global__ __launch_bounds__(256)
void prep_w(const float* __restrict__ Wq, const float* __restrict__ Wk,
            const float* __restrict__ Wv, unsigned short* __restrict__ wt) {
    const int id = blockIdx.x * 256 + threadIdx.x;
    const int sel = id / (EP * KP);
    const int rem = id % (EP * KP);
    const int e = rem / KP;
    const int k = rem % KP;
    const float* W = (sel == 0) ? Wq : ((sel == 1) ? Wk : Wv);
    float v = (e < E_ && k < F_) ? W[(size_t)k * E_ + e] : 0.0f;
    wt[id] = f2bf(v);
}

// ---------------- Stage 1 GEMM: Q/K/V = gelu(Xb @ W) ----------------
// (unchanged from the round-13 passing source)
#define STAGE(XB, WB, KK) do {                                                   \
    const int k0s = (KK) * 32;                                                   \
    _Pragma("unroll")                                                            \
    for (int i = 0; i < 2; ++i) {                                                \
        const int j = w * 2 + i;                                                 \
        const int row = 16 * j + rS;                                             \
        gload_lds16(xb + (size_t)(m0 + row) * KP + k0s + ((pS ^ (row & 3)) * 8), \
                    &XB[j * 512]);                                               \
    }                                                                            \
    _Pragma("unroll")                                                            \
    for (int i = 0; i < 4; ++i) {                                                \
        const int j = i * 4 + w;                                                 \
        if (j < 14) {                                                            \
            const int row = 16 * j + rS;                                         \
            gload_lds16(wsel + (size_t)row * KP + k0s + ((pS ^ (row & 3)) * 8),  \
                        &WB[j * 512]);                                           \
        }                                                                        \
    }                                                                            \
} while (0)

#define COMPUTE(XB, WB) do {                                                     \
    short8 afr[4];                                                               \
    _Pragma("unroll")                                                            \
    for (int rf = 0; rf < 4; ++rf) {                                             \
        const int row = wr * 64 + rf * 16 + ln15;                                \
        afr[rf] = *reinterpret_cast<const short8*>(                              \
            &XB[row * 32 + ((g ^ (row & 3)) * 8)]);                              \
    }                                                                            \
    _Pragma("unroll")                                                            \
    for (int cf = 0; cf < 7; ++cf) {                                             \
        const int row = wc * 112 + cf * 16 + ln15;                               \
        short8 bfr = *reinterpret_cast<const short8*>(                           \
            &WB[row * 32 + ((g ^ (row & 3)) * 8)]);                              \
        _Pragma("unroll")                                                        \
        for (int rf = 0; rf < 4; ++rf)                                           \
            acc[rf][cf] = __builtin_amdgcn_mfma_f32_16x16x32_bf16(               \
                afr[rf], bfr, acc[rf][cf], 0, 0, 0);                             \
    }                                                                            \
} while (0)

__global__ __launch_bounds__(256, 2)
void gemm_qkv(const unsigned short* __restrict__ xb,
              const unsigned short* __restrict__ wt,
              unsigned short* __restrict__ qbuf,
              unsigned short* __restrict__ kbuf,
              unsigned short* __restrict__ vtbuf) {
    const int sel = blockIdx.y;
    const int m0 = blockIdx.x * 128;
    const int t = threadIdx.x;
    const int lane = t & 63;
    const int w = t >> 6;
    const int wr = w >> 1;
    const int wc = w & 1;
    const int ln15 = lane & 15;
    const int g = lane >> 4;

    __shared__ __align__(16) unsigned short X0s[128 * 32];
    __shared__ __align__(16) unsigned short W0s[224 * 32];
    __shared__ __align__(16) unsigned short X1s[128 * 32];
    __shared__ __align__(16) unsigned short W1s[224 * 32];

    const unsigned short* wsel = wt + (size_t)sel * EP * KP;

    f32x4 acc[4][7];
#pragma unroll
    for (int i = 0; i < 4; ++i)
#pragma unroll
        for (int j = 0; j < 7; ++j) acc[i][j] = (f32x4)0.0f;

    const int rS = lane >> 2;            // staging row within 16-row chunk
    const int pS = lane & 3;             // staging physical granule

    STAGE(X0s, W0s, 0);
    __syncthreads();
#pragma unroll
    for (int p = 0; p < 12; ++p) {
        STAGE(X1s, W1s, 2 * p + 1);
        COMPUTE(X0s, W0s);
        __syncthreads();
        STAGE(X0s, W0s, 2 * p + 2);
        COMPUTE(X1s, W1s);
        __syncthreads();
    }
    STAGE(X1s, W1s, 25);
    COMPUTE(X0s, W0s);                   // kk = 24
    __syncthreads();
    COMPUTE(X1s, W1s);                   // kk = 25

    // epilogue: gelu + store; V padding col 200 <- 1.0 (ones-column: PV
    // MFMA computes softmax denominators for free in attn)
#pragma unroll
    for (int rf = 0; rf < 4; ++rf) {
        const int row = m0 + wr * 64 + rf * 16 + g * 4;
#pragma unroll
        for (int cf = 0; cf < 7; ++cf) {
            const int col = wc * 112 + cf * 16 + ln15;
            if (sel == 0) {
#pragma unroll
                for (int tt = 0; tt < 4; ++tt)
                    qbuf[(size_t)(row + tt) * EP + col] =
                        f2bf(gelu_fast(acc[rf][cf][tt]) * QSCL);
            } else if (sel == 1) {
#pragma unroll
                for (int tt = 0; tt < 4; ++tt)
                    kbuf[(size_t)(row + tt) * KSP + col] = f2bf(gelu_fast(acc[rf][cf][tt]));
            } else {
                const int bb = row >> 11, s = row & 2047;
                ushort4 pk;
                if (col == 200) {
                    pk.x = 0x3F80; pk.y = 0x3F80; pk.z = 0x3F80; pk.w = 0x3F80;
                } else {
                    pk.x = f2bf(gelu_fast(acc[rf][cf][0]));
                    pk.y = f2bf(gelu_fast(acc[rf][cf][1]));
                    pk.z = f2bf(gelu_fast(acc[rf][cf][2]));
                    pk.w = f2bf(gelu_fast(acc[rf][cf][3]));
                }
                *reinterpret_cast<ushort4*>(
                    &vtbuf[((size_t)(bb * EP + col)) * S_ + s]) = pk;
            }
        }
    }
}

// ---------------- Stage 2: flash attention (R5 tiles, 8 waves) ----------
// BQ=128, 8 waves x 16 q-rows (512 threads), BKV=64 double-buffered, R5's
// exact staging/swizzles/schedule. Registers/thread halved vs R5 (o[14]+qf[7]
// ~110 VGPR) -> fits launch_bounds(512,2) cap of 256 with NO spill (the
// spill+gload_lds interaction is the prime suspect for R6/R11/R12/R14 fails).
// 2 waves/SIMD for latency hiding; LDS 138KB -> 1 block/CU.
#define BQ  128
#define BKV 64

#define ASTAGE(KB, VB, KT) do {                                                  \
    const int kv0s = (KT) * BKV;                                                 \
    {   /* K: 32 x 1KB calls, 4 per wave, 2 rows each */                         \
        const int r_in = lane >> 5;                                              \
        const int p = lane & 31;                                                 \
        _Pragma("unroll")                                                        \
        for (int i = 0; i < 4; ++i) {                                            \
            const int j = w * 4 + i;                                             \
            const int row = 2 * j + r_in;                                        \
            gload_lds16(kb_b + (size_t)(kv0s + row) * KSP + ((p ^ (row & 7)) * 8),\
                        &KB[j * 512]);                                           \
        }                                                                        \
    }                                                                            \
    {   /* V: 28 x 1KB calls, 8 rows each */                                     \
        const int r_in = lane >> 3;                                              \
        const int p = lane & 7;                                                  \
        _Pragma("unroll")                                                        \
        for (int i = 0; i < 4; ++i) {                                            \
            const int j = i * 8 + w;                                             \
            if (j < 28) {                                                        \
                const int row = 8 * j + r_in;                                    \
                gload_lds16(vt_b + (size_t)row * S_ + kv0s + ((p ^ (row & 7)) * 8),\
                            &VB[j * 512]);                                       \
            }                                                                    \
        }                                                                        \
    }                                                                            \
} while (0)

#define ACOMPUTE(KB, VB) do {                                                    \
    f32x4 sacc[4];                                                               \
    _Pragma("unroll")                                                            \
    for (int n = 0; n < 4; ++n) {                                                \
        f32x4 a = (f32x4)0.0f;                                                   \
        const int krow = n * 16 + ln15;                                          \
        const unsigned short* kr = &KB[krow * KSP];                              \
        const int rx = krow & 7;                                                 \
        _Pragma("unroll")                                                        \
        for (int s = 0; s < 7; ++s) {                                            \
            short8 bf = *reinterpret_cast<const short8*>(                        \
                kr + (((s * 4 + g) ^ rx) * 8));                                  \
            a = __builtin_amdgcn_mfma_f32_16x16x32_bf16(qf[s], bf, a, 0, 0, 0);  \
        }                                                                        \
        sacc[n] = a;                                                             \
    }                                                                            \
    _Pragma("unroll")                                                            \
    for (int n = 0; n < 4; ++n)                                                  \
        _Pragma("unroll")                                                        \
        for (int tt = 0; tt < 4; ++tt)                                           \
            Plds[w][g * 4 + tt][n * 16 + ln15] = f2bf(exp2_fast(sacc[n][tt]));   \
    short8 pf0 = *reinterpret_cast<const short8*>(&Plds[w][ln15][g * 8]);        \
    short8 pf1 = *reinterpret_cast<const short8*>(&Plds[w][ln15][32 + g * 8]);   \
    _Pragma("unroll")                                                            \
    for (int n = 0; n < 14; ++n) {                                               \
        const int vrow = n * 16 + ln15;                                          \
        const unsigned short* vr = &VB[vrow * 64];                               \
        const int rx = vrow & 7;                                                 \
        short8 b0 = *reinterpret_cast<const short8*>(vr + ((g ^ rx) * 8));       \
        short8 b1 = *reinterpret_cast<const short8*>(vr + (((4 + g) ^ rx) * 8)); \
        o[n] = __builtin_amdgcn_mfma_f32_16x16x32_bf16(pf0, b0, o[n], 0, 0, 0);  \
        o[n] = __builtin_amdgcn_mfma_f32_16x16x32_bf16(pf1, b1, o[n], 0, 0, 0);  \
    }                                                                            \
} while (0)

__global__ __launch_bounds__(512, 2)
void attn_kernel(const unsigned short* __restrict__ qbuf,
                 const unsigned short* __restrict__ kbuf,
                 const unsigned short* __restrict__ vtbuf,
                 float* __restrict__ out) {
    // XCD-aware role remap: XCD c serves batches {2c, 2c+1} (K/V 3.6MB < 4MB L2)
    const int id = blockIdx.x;            // 0..255
    const int slot = id >> 3;             // 0..31
    const int b = 2 * (id & 7) + (slot >> 4);
    const int q0 = (slot & 15) * BQ;
    const int t = threadIdx.x;
    const int lane = t & 63;
    const int w = t >> 6;                 // 0..7
    const int ln15 = lane & 15;
    const int g = lane >> 4;              // 0..3

    __shared__ __align__(16) unsigned short Ks[2][BKV * KSP];   // 2 x 32KB
    __shared__ __align__(16) unsigned short Vts[2][EP * 64];    // 2 x 28KB
    __shared__ __align__(16) unsigned short Plds[8][16][68];    // 17KB

    // Q fragments: 16 rows per wave (pre-scaled by scale*log2e)
    short8 qf[7];
    {
        const unsigned short* qp =
            qbuf + (size_t)(b * S_ + q0 + w * 16 + ln15) * EP + g * 8;
#pragma unroll
        for (int s = 0; s < 7; ++s)
            qf[s] = *reinterpret_cast<const short8*>(qp + s * 32);
    }

    f32x4 o[14];
#pragma unroll
    for (int i = 0; i < 14; ++i) o[i] = (f32x4)0.0f;

    const unsigned short* kb_b = kbuf + (size_t)b * S_ * KSP;
    const unsigned short* vt_b = vtbuf + (size_t)b * EP * S_;

    ASTAGE(Ks[0], Vts[0], 0);
    __syncthreads();
    for (int kt = 0; kt < S_ / BKV - 1; ++kt) {
        const int cur = kt & 1;
        ASTAGE(Ks[cur ^ 1], Vts[cur ^ 1], kt + 1);
        ACOMPUTE(Ks[cur], Vts[cur]);
        __syncthreads();
    }
    ACOMPUTE(Ks[1], Vts[1]);              // tile 31 (odd -> buffer 1)

    // epilogue: l = o[12] at col 200 (ln15==8); broadcast, normalize, store
    {
        float l[4];
#pragma unroll
        for (int tt = 0; tt < 4; ++tt)
            l[tt] = __shfl(o[12][tt], (lane & 48) + 8, 64);
#pragma unroll
        for (int tt = 0; tt < 4; ++tt) {
            const float inv = 1.0f / l[tt];
            const int row = q0 + w * 16 + g * 4 + tt;
            float* op = out + (size_t)(b * S_ + row) * E_;
#pragma unroll
            for (int n = 0; n < 13; ++n) {
                const int e = n * 16 + ln15;
                if (e < E_) op[e] = o[n][tt] * inv;
            }
        }
    }
}

extern "C" void kernel_launch(void* const* d_in, const int* in_sizes, int n_in,
                              void* d_out, int out_size, void* d_ws, size_t ws_size,
                              hipStream_t stream) {
    const float* x  = (const float*)d_in[0];
    const float* Wq = (const float*)d_in[1];
    const float* Wk = (const float*)d_in[2];
    const float* Wv = (const float*)d_in[3];
    float* out = (float*)d_out;

    unsigned short* xb    = (unsigned short*)d_ws;                 // [M_][KP]
    unsigned short* wt    = xb + (size_t)M_ * KP;                  // [3][EP][KP]
    unsigned short* qbuf  = wt + (size_t)3 * EP * KP;              // [M_][EP]
    unsigned short* kbuf  = qbuf + (size_t)M_ * EP;                // [M_][KSP]
    unsigned short* vtbuf = kbuf + (size_t)M_ * KSP;               // [B_][EP][S_]

    prep_x<<<dim3(M_ * (KP / 8) / 256), 256, 0, stream>>>(x, xb);
    prep_w<<<dim3(3 * EP * KP / 256), 256, 0, stream>>>(Wq, Wk, Wv, wt);
    gemm_qkv<<<dim3(256, 3), 256, 0, stream>>>(xb, wt, qbuf, kbuf, vtbuf);
    attn_kernel<<<dim3(256), 512, 0, stream>>>(qbuf, kbuf, vtbuf, out);
}